// Round 1
// baseline (2788.313 us; speedup 1.0000x reference)
//
#include <hip/hip_runtime.h>

// ---------------------------------------------------------------------------
// GPN_GCN: GCNConv x2 -> classifier (2 small GEMMs) -> APPNP(10) -> log_softmax
// Strategy: build CSR (by target) once per launch, then all propagations are
// gathers (no float atomics). fp32 everywhere (correctness-first).
// ---------------------------------------------------------------------------

__global__ __launch_bounds__(256) void k_init(int* deg, int* cursor, int N) {
    int i = blockIdx.x * 256 + threadIdx.x;
    if (i < N) { deg[i] = 1; cursor[i] = 0; }  // deg=1 accounts for self-loop
}

__global__ __launch_bounds__(256) void k_count(const int* __restrict__ dst, int* deg, int E) {
    int e = blockIdx.x * 256 + threadIdx.x;
    if (e < E) atomicAdd(&deg[dst[e]], 1);
}

// Per-block sums of (deg-1) -> bs[block]
__global__ __launch_bounds__(256) void k_scanA(const int* __restrict__ deg, int* bs, int N) {
    __shared__ int s[256];
    int t = threadIdx.x;
    int i = blockIdx.x * 256 + t;
    int c = (i < N) ? (deg[i] - 1) : 0;
    s[t] = c; __syncthreads();
    for (int o = 128; o > 0; o >>= 1) {
        if (t < o) s[t] += s[t + o];
        __syncthreads();
    }
    if (t == 0) bs[blockIdx.x] = s[0];
}

// Exclusive scan of block sums (NB <= 512), single block
__global__ __launch_bounds__(512) void k_scanB(int* bs, int NB) {
    __shared__ int s[512];
    int t = threadIdx.x;
    int v = (t < NB) ? bs[t] : 0;
    s[t] = v; __syncthreads();
    for (int o = 1; o < 512; o <<= 1) {
        int u = (t >= o) ? s[t - o] : 0;
        __syncthreads();
        s[t] += u;
        __syncthreads();
    }
    if (t < NB) bs[t] = s[t] - v;  // exclusive
}

// row_ptr[i] = exclusive prefix of (deg-1); also dinv = rsqrt(deg)
__global__ __launch_bounds__(256) void k_scanC(const int* __restrict__ deg, const int* __restrict__ bs,
                                               int* row_ptr, float* dinv, int N) {
    __shared__ int s[256];
    int t = threadIdx.x;
    int i = blockIdx.x * 256 + t;
    int c = (i < N) ? (deg[i] - 1) : 0;
    s[t] = c; __syncthreads();
    for (int o = 1; o < 256; o <<= 1) {
        int u = (t >= o) ? s[t - o] : 0;
        __syncthreads();
        s[t] += u;
        __syncthreads();
    }
    if (i < N) {
        int off = bs[blockIdx.x];
        row_ptr[i] = off + s[t] - c;          // exclusive
        dinv[i] = rsqrtf((float)deg[i]);      // deg >= 1 always
        if (i == N - 1) row_ptr[N] = off + s[t];
    }
}

__global__ __launch_bounds__(256) void k_fill(const int* __restrict__ src, const int* __restrict__ dst,
                                              const int* __restrict__ row_ptr, int* cursor,
                                              int* csr_src, int E) {
    int e = blockIdx.x * 256 + threadIdx.x;
    if (e < E) {
        int d = dst[e];
        int pos = row_ptr[d] + atomicAdd(&cursor[d], 1);
        csr_src[pos] = src[e];
    }
}

// Y[M,128] = X[M,K] @ W[K,128].  16 rows per block, thread = col x 8 rows.
template <int K>
__global__ __launch_bounds__(256) void k_gemm128(const float* __restrict__ X,
                                                 const float* __restrict__ W,
                                                 float* __restrict__ Y) {
    __shared__ float xs[16 * K];
    int tid = threadIdx.x;
    int col = tid & 127;
    int half = tid >> 7;  // 0..1
    long rowBase = (long)blockIdx.x * 16;

    const float4* xg = (const float4*)(X + rowBase * K);
    float4* xs4 = (float4*)xs;
#pragma unroll
    for (int i = tid; i < 16 * K / 4; i += 256) xs4[i] = xg[i];
    __syncthreads();

    float acc[8];
#pragma unroll
    for (int r = 0; r < 8; r++) acc[r] = 0.f;
    int r0 = half * 8;
    for (int k = 0; k < K; k += 4) {
        float w0 = W[(k + 0) * 128 + col];
        float w1 = W[(k + 1) * 128 + col];
        float w2 = W[(k + 2) * 128 + col];
        float w3 = W[(k + 3) * 128 + col];
#pragma unroll
        for (int r = 0; r < 8; r++) {
            const float4 xv = *(const float4*)&xs[(r0 + r) * K + k];
            acc[r] += xv.x * w0 + xv.y * w1 + xv.z * w2 + xv.w * w3;
        }
    }
#pragma unroll
    for (int r = 0; r < 8; r++) Y[(rowBase + r0 + r) * 128 + col] = acc[r];
}

// Gather-based propagation. out[i] = dinv[i]*sum_{e:col=i} dinv[src]*h[src]
//                                    + dinv[i]^2*h[i]   (self loop)
// MODE 0: out = relu(out + bias[f])     (GCN layer)
// MODE 1: out = 0.9*out + 0.1*ev[i,f]   (APPNP step)
template <int F, int MODE>
__global__ __launch_bounds__(256) void k_prop(const float* __restrict__ hin,
                                              const int* __restrict__ row_ptr,
                                              const int* __restrict__ csr_src,
                                              const float* __restrict__ dinv,
                                              const float* __restrict__ bias,
                                              const float* __restrict__ ev,
                                              float* __restrict__ hout, int N) {
    const int npb = 256 / F;
    int node = blockIdx.x * npb + threadIdx.x / F;
    int f = threadIdx.x % F;
    if (node >= N) return;
    int s = row_ptr[node], e = row_ptr[node + 1];
    float acc = 0.f;
    for (int j = s; j < e; j++) {
        int src = csr_src[j];
        acc += dinv[src] * hin[(long)src * F + f];
    }
    float di = dinv[node];
    float v = di * acc + di * di * hin[(long)node * F + f];
    if (MODE == 0) {
        v = fmaxf(v + bias[f], 0.f);
    } else {
        v = 0.9f * v + 0.1f * ev[(long)node * F + f];
    }
    hout[(long)node * F + f] = v;
}

// ev = relu((H@Wc + bc)@We + be), fused. 16 nodes per block, weights in LDS.
__global__ __launch_bounds__(256) void k_classifier(const float* __restrict__ H,
                                                    const float* __restrict__ Wc,
                                                    const float* __restrict__ bc,
                                                    const float* __restrict__ We,
                                                    const float* __restrict__ be,
                                                    float* __restrict__ ev, int N) {
    __shared__ float sWc[128 * 64];
    __shared__ float sWe[64 * 64];
    __shared__ float sH[16 * 128];
    __shared__ float sL[16 * 64];
    __shared__ float sbc[64], sbe[64];
    int tid = threadIdx.x;
    long nodeBase = (long)blockIdx.x * 16;

    {
        float4* p = (float4*)sWc; const float4* g = (const float4*)Wc;
        for (int i = tid; i < 128 * 64 / 4; i += 256) p[i] = g[i];
        p = (float4*)sWe; g = (const float4*)We;
        for (int i = tid; i < 64 * 64 / 4; i += 256) p[i] = g[i];
        p = (float4*)sH; g = (const float4*)(H + nodeBase * 128);
        for (int i = tid; i < 16 * 128 / 4; i += 256) p[i] = g[i];
        if (tid < 64) { sbc[tid] = bc[tid]; sbe[tid] = be[tid]; }
    }
    __syncthreads();

    int c = tid & 63, grp = tid >> 6;
    for (int nl = grp; nl < 16; nl += 4) {
        float l = sbc[c];
#pragma unroll 4
        for (int k = 0; k < 128; k++) l += sH[nl * 128 + k] * sWc[k * 64 + c];
        sL[nl * 64 + c] = l;
    }
    __syncthreads();
    for (int nl = grp; nl < 16; nl += 4) {
        float v = sbe[c];
#pragma unroll 4
        for (int j = 0; j < 64; j++) v += sL[nl * 64 + j] * sWe[j * 64 + c];
        ev[(nodeBase + nl) * 64 + c] = fmaxf(v, 0.f);
    }
}

// log_softmax over 64 classes: one wave per node, lane = class
__global__ __launch_bounds__(256) void k_logsoftmax(const float* __restrict__ Z,
                                                    float* __restrict__ out, int N) {
    int node = blockIdx.x * 4 + (threadIdx.x >> 6);
    int c = threadIdx.x & 63;
    if (node >= N) return;
    float v = Z[(long)node * 64 + c];
    float m = v;
    for (int o = 32; o > 0; o >>= 1) m = fmaxf(m, __shfl_xor(m, o, 64));
    float ex = __expf(v - m);
    float ssum = ex;
    for (int o = 32; o > 0; o >>= 1) ssum += __shfl_xor(ssum, o, 64);
    out[(long)node * 64 + c] = v - m - __logf(ssum);
}

extern "C" void kernel_launch(void* const* d_in, const int* in_sizes, int n_in,
                              void* d_out, int out_size, void* d_ws, size_t ws_size,
                              hipStream_t stream) {
    const float* x  = (const float*)d_in[0];
    const int* edges = (const int*)d_in[1];   // [2,E] int32 (harness convention)
    const float* W1 = (const float*)d_in[2];
    const float* b1 = (const float*)d_in[3];
    const float* W2 = (const float*)d_in[4];
    const float* b2 = (const float*)d_in[5];
    const float* Wc = (const float*)d_in[6];
    const float* bc = (const float*)d_in[7];
    const float* We = (const float*)d_in[8];
    const float* be = (const float*)d_in[9];

    const int N = in_sizes[0] / 256;   // 100000
    const int E = in_sizes[1] / 2;     // 1600000
    const int* esrc = edges;
    const int* edst = edges + E;

    // workspace carve-up
    char* ws = (char*)d_ws;
    size_t off = 0;
    auto alloc = [&](size_t bytes) -> void* {
        void* p = ws + off;
        off += (bytes + 255) & ~(size_t)255;
        return p;
    };
    int*   deg     = (int*)alloc((size_t)N * 4);
    int*   cursor  = (int*)alloc((size_t)N * 4);
    int*   row_ptr = (int*)alloc((size_t)(N + 1) * 4);
    float* dinv    = (float*)alloc((size_t)N * 4);
    int*   bs      = (int*)alloc(4096 * 4);
    int*   csr_src = (int*)alloc((size_t)E * 4);
    float* P       = (float*)alloc((size_t)N * 128 * 4);
    float* Q       = (float*)alloc((size_t)N * 128 * 4);
    float* zA      = (float*)alloc((size_t)N * 64 * 4);
    float* zB      = (float*)alloc((size_t)N * 64 * 4);
    float* ev      = (float*)d_out;  // lives in d_out until final log_softmax

    const int nbN = (N + 255) / 256;
    const int nbE = (E + 255) / 256;

    // --- CSR build ---
    k_init<<<nbN, 256, 0, stream>>>(deg, cursor, N);
    k_count<<<nbE, 256, 0, stream>>>(edst, deg, E);
    k_scanA<<<nbN, 256, 0, stream>>>(deg, bs, N);
    k_scanB<<<1, 512, 0, stream>>>(bs, nbN);
    k_scanC<<<nbN, 256, 0, stream>>>(deg, bs, row_ptr, dinv, N);
    k_fill<<<nbE, 256, 0, stream>>>(esrc, edst, row_ptr, cursor, csr_src, E);

    // --- GCN layer 1: P = x@W1 ; Q = relu(prop(P)+b1) ---
    k_gemm128<256><<<N / 16, 256, 0, stream>>>(x, W1, P);
    k_prop<128, 0><<<N / 2, 256, 0, stream>>>(P, row_ptr, csr_src, dinv, b1, nullptr, Q, N);

    // --- GCN layer 2: P = Q@W2 ; Q = relu(prop(P)+b2) ---
    k_gemm128<128><<<N / 16, 256, 0, stream>>>(Q, W2, P);
    k_prop<128, 0><<<N / 2, 256, 0, stream>>>(P, row_ptr, csr_src, dinv, b2, nullptr, Q, N);

    // --- classifier: ev = relu((Q@Wc+bc)@We+be) ---
    k_classifier<<<N / 16, 256, 0, stream>>>(Q, Wc, bc, We, be, ev, N);

    // --- APPNP: z = 0.9*prop(z) + 0.1*ev, 10 iters ---
    const float* zin = ev;
    float* zout = zA;
    for (int it = 0; it < 10; ++it) {
        k_prop<64, 1><<<N / 4, 256, 0, stream>>>(zin, row_ptr, csr_src, dinv, nullptr, ev, zout, N);
        zin = zout;
        zout = (it % 2 == 0) ? zB : zA;
    }
    // zin == zB after 10 iters

    // --- log_softmax -> d_out (overwrites ev after its last use) ---
    k_logsoftmax<<<(N + 3) / 4, 256, 0, stream>>>(zin, (float*)d_out, N);
}

// Round 2
// 1609.016 us; speedup vs baseline: 1.7329x; 1.7329x over previous
//
#include <hip/hip_runtime.h>

// ---------------------------------------------------------------------------
// GPN_GCN: GCNConv x2 -> classifier -> APPNP(10) -> log_softmax
// CSR built per launch; propagations are wave-per-node float4 gathers with
// edge-slot parallelism + 2x unroll (MLP). dinv folded into the gathered
// tables (scaled representation) so the per-edge work is one 16B load + adds.
// ---------------------------------------------------------------------------

__global__ __launch_bounds__(256) void k_init(int* deg, int* cursor, int N) {
    int i = blockIdx.x * 256 + threadIdx.x;
    if (i < N) { deg[i] = 1; cursor[i] = 0; }  // deg=1 accounts for self-loop
}

__global__ __launch_bounds__(256) void k_count(const int* __restrict__ dst, int* deg, int E) {
    int e = blockIdx.x * 256 + threadIdx.x;
    if (e < E) atomicAdd(&deg[dst[e]], 1);
}

__global__ __launch_bounds__(256) void k_scanA(const int* __restrict__ deg, int* bs, int N) {
    __shared__ int s[256];
    int t = threadIdx.x;
    int i = blockIdx.x * 256 + t;
    int c = (i < N) ? (deg[i] - 1) : 0;
    s[t] = c; __syncthreads();
    for (int o = 128; o > 0; o >>= 1) {
        if (t < o) s[t] += s[t + o];
        __syncthreads();
    }
    if (t == 0) bs[blockIdx.x] = s[0];
}

__global__ __launch_bounds__(512) void k_scanB(int* bs, int NB) {
    __shared__ int s[512];
    int t = threadIdx.x;
    int v = (t < NB) ? bs[t] : 0;
    s[t] = v; __syncthreads();
    for (int o = 1; o < 512; o <<= 1) {
        int u = (t >= o) ? s[t - o] : 0;
        __syncthreads();
        s[t] += u;
        __syncthreads();
    }
    if (t < NB) bs[t] = s[t] - v;  // exclusive
}

__global__ __launch_bounds__(256) void k_scanC(const int* __restrict__ deg, const int* __restrict__ bs,
                                               int* row_ptr, float* dinv, int N) {
    __shared__ int s[256];
    int t = threadIdx.x;
    int i = blockIdx.x * 256 + t;
    int c = (i < N) ? (deg[i] - 1) : 0;
    s[t] = c; __syncthreads();
    for (int o = 1; o < 256; o <<= 1) {
        int u = (t >= o) ? s[t - o] : 0;
        __syncthreads();
        s[t] += u;
        __syncthreads();
    }
    if (i < N) {
        int off = bs[blockIdx.x];
        row_ptr[i] = off + s[t] - c;          // exclusive
        dinv[i] = rsqrtf((float)deg[i]);
        if (i == N - 1) row_ptr[N] = off + s[t];
    }
}

__global__ __launch_bounds__(256) void k_fill(const int* __restrict__ src, const int* __restrict__ dst,
                                              const int* __restrict__ row_ptr, int* cursor,
                                              int* csr_src, int E) {
    int e = blockIdx.x * 256 + threadIdx.x;
    if (e < E) {
        int d = dst[e];
        int pos = row_ptr[d] + atomicAdd(&cursor[d], 1);
        csr_src[pos] = src[e];
    }
}

// Y[M,128] = dinv[row] * (X[M,K] @ W[K,128]).  16 rows/block.
template <int K>
__global__ __launch_bounds__(256) void k_gemm128(const float* __restrict__ X,
                                                 const float* __restrict__ W,
                                                 const float* __restrict__ dinv,
                                                 float* __restrict__ Y) {
    __shared__ float xs[16 * K];
    int tid = threadIdx.x;
    int col = tid & 127;
    int half = tid >> 7;
    long rowBase = (long)blockIdx.x * 16;

    const float4* xg = (const float4*)(X + rowBase * K);
    float4* xs4 = (float4*)xs;
#pragma unroll
    for (int i = tid; i < 16 * K / 4; i += 256) xs4[i] = xg[i];
    __syncthreads();

    float acc[8];
#pragma unroll
    for (int r = 0; r < 8; r++) acc[r] = 0.f;
    int r0 = half * 8;
    for (int k = 0; k < K; k += 4) {
        float w0 = W[(k + 0) * 128 + col];
        float w1 = W[(k + 1) * 128 + col];
        float w2 = W[(k + 2) * 128 + col];
        float w3 = W[(k + 3) * 128 + col];
#pragma unroll
        for (int r = 0; r < 8; r++) {
            const float4 xv = *(const float4*)&xs[(r0 + r) * K + k];
            acc[r] += xv.x * w0 + xv.y * w1 + xv.z * w2 + xv.w * w3;
        }
    }
#pragma unroll
    for (int r = 0; r < 8; r++) {
        long row = rowBase + r0 + r;
        Y[row * 128 + col] = acc[r] * dinv[row];
    }
}

// Wave-per-node gather propagation over scaled table tab = dinv (.) h.
// A = sum_{src in nbr(i)} tab[src] + tab[i]   (self loop folded in)
// MODE 0 (GCN):         out = relu(di*A + bias)            (out unscaled)
// MODE 1 (APPNP inner): out = 0.9*di^2*A + 0.1*evs[i]      (out scaled)
// MODE 2 (APPNP final): out = 0.9*di*A  + 0.1*ev[i]        (out unscaled)
template <int F, int MODE>
__global__ __launch_bounds__(256) void k_prop2(const float* __restrict__ tab,
                                               const int* __restrict__ row_ptr,
                                               const int* __restrict__ csr_src,
                                               const float* __restrict__ dinv,
                                               const float* __restrict__ bias,
                                               const float* __restrict__ evx,
                                               float* __restrict__ out, int N) {
    constexpr int LPE = F / 4;    // lanes per edge-slot (float4 each)
    constexpr int S = 64 / LPE;   // edge slots per wave
    int wave = threadIdx.x >> 6;
    int lane = threadIdx.x & 63;
    int node = blockIdx.x * 4 + wave;
    if (node >= N) return;
    int slot = lane / LPE;
    int fl = lane % LPE;          // features 4*fl .. 4*fl+3
    int s = row_ptr[node], e = row_ptr[node + 1];

    float4 acc0 = {0.f, 0.f, 0.f, 0.f};
    float4 acc1 = {0.f, 0.f, 0.f, 0.f};
    int j = s + slot;
    for (; j + S < e; j += 2 * S) {
        int s0 = csr_src[j];
        int s1 = csr_src[j + S];
        const float4 a = *(const float4*)&tab[(long)s0 * F + 4 * fl];
        const float4 b = *(const float4*)&tab[(long)s1 * F + 4 * fl];
        acc0.x += a.x; acc0.y += a.y; acc0.z += a.z; acc0.w += a.w;
        acc1.x += b.x; acc1.y += b.y; acc1.z += b.z; acc1.w += b.w;
    }
    if (j < e) {
        int s0 = csr_src[j];
        const float4 a = *(const float4*)&tab[(long)s0 * F + 4 * fl];
        acc0.x += a.x; acc0.y += a.y; acc0.z += a.z; acc0.w += a.w;
    }
    if (slot == 0) {  // self loop
        const float4 a = *(const float4*)&tab[(long)node * F + 4 * fl];
        acc0.x += a.x; acc0.y += a.y; acc0.z += a.z; acc0.w += a.w;
    }
    acc0.x += acc1.x; acc0.y += acc1.y; acc0.z += acc1.z; acc0.w += acc1.w;

#pragma unroll
    for (int off = LPE; off < 64; off <<= 1) {
        acc0.x += __shfl_xor(acc0.x, off, 64);
        acc0.y += __shfl_xor(acc0.y, off, 64);
        acc0.z += __shfl_xor(acc0.z, off, 64);
        acc0.w += __shfl_xor(acc0.w, off, 64);
    }

    if (slot == 0) {
        float di = dinv[node];
        float4 v;
        if (MODE == 0) {
            const float4 b4 = *(const float4*)&bias[4 * fl];
            v.x = fmaxf(di * acc0.x + b4.x, 0.f);
            v.y = fmaxf(di * acc0.y + b4.y, 0.f);
            v.z = fmaxf(di * acc0.z + b4.z, 0.f);
            v.w = fmaxf(di * acc0.w + b4.w, 0.f);
        } else if (MODE == 1) {
            float d2 = 0.9f * di * di;
            const float4 e4 = *(const float4*)&evx[(long)node * F + 4 * fl];
            v.x = d2 * acc0.x + 0.1f * e4.x;
            v.y = d2 * acc0.y + 0.1f * e4.y;
            v.z = d2 * acc0.z + 0.1f * e4.z;
            v.w = d2 * acc0.w + 0.1f * e4.w;
        } else {
            float d1 = 0.9f * di;
            const float4 e4 = *(const float4*)&evx[(long)node * F + 4 * fl];
            v.x = d1 * acc0.x + 0.1f * e4.x;
            v.y = d1 * acc0.y + 0.1f * e4.y;
            v.z = d1 * acc0.z + 0.1f * e4.z;
            v.w = d1 * acc0.w + 0.1f * e4.w;
        }
        *(float4*)&out[(long)node * F + 4 * fl] = v;
    }
}

// ev = relu((H@Wc + bc)@We + be); also writes evs = dinv (.) ev.
__global__ __launch_bounds__(256) void k_classifier(const float* __restrict__ H,
                                                    const float* __restrict__ Wc,
                                                    const float* __restrict__ bc,
                                                    const float* __restrict__ We,
                                                    const float* __restrict__ be,
                                                    const float* __restrict__ dinv,
                                                    float* __restrict__ ev,
                                                    float* __restrict__ evs, int N) {
    __shared__ float sWc[128 * 64];
    __shared__ float sWe[64 * 64];
    __shared__ float sH[16 * 128];
    __shared__ float sL[16 * 64];
    __shared__ float sbc[64], sbe[64];
    int tid = threadIdx.x;
    long nodeBase = (long)blockIdx.x * 16;

    {
        float4* p = (float4*)sWc; const float4* g = (const float4*)Wc;
        for (int i = tid; i < 128 * 64 / 4; i += 256) p[i] = g[i];
        p = (float4*)sWe; g = (const float4*)We;
        for (int i = tid; i < 64 * 64 / 4; i += 256) p[i] = g[i];
        p = (float4*)sH; g = (const float4*)(H + nodeBase * 128);
        for (int i = tid; i < 16 * 128 / 4; i += 256) p[i] = g[i];
        if (tid < 64) { sbc[tid] = bc[tid]; sbe[tid] = be[tid]; }
    }
    __syncthreads();

    int c = tid & 63, grp = tid >> 6;
    for (int nl = grp; nl < 16; nl += 4) {
        float l = sbc[c];
#pragma unroll 4
        for (int k = 0; k < 128; k++) l += sH[nl * 128 + k] * sWc[k * 64 + c];
        sL[nl * 64 + c] = l;
    }
    __syncthreads();
    for (int nl = grp; nl < 16; nl += 4) {
        float v = sbe[c];
#pragma unroll 4
        for (int j = 0; j < 64; j++) v += sL[nl * 64 + j] * sWe[j * 64 + c];
        v = fmaxf(v, 0.f);
        long node = nodeBase + nl;
        ev[node * 64 + c] = v;
        evs[node * 64 + c] = v * dinv[node];
    }
}

__global__ __launch_bounds__(256) void k_logsoftmax(const float* __restrict__ Z,
                                                    float* __restrict__ out, int N) {
    int node = blockIdx.x * 4 + (threadIdx.x >> 6);
    int c = threadIdx.x & 63;
    if (node >= N) return;
    float v = Z[(long)node * 64 + c];
    float m = v;
    for (int o = 32; o > 0; o >>= 1) m = fmaxf(m, __shfl_xor(m, o, 64));
    float ex = __expf(v - m);
    float ssum = ex;
    for (int o = 32; o > 0; o >>= 1) ssum += __shfl_xor(ssum, o, 64);
    out[(long)node * 64 + c] = v - m - __logf(ssum);
}

extern "C" void kernel_launch(void* const* d_in, const int* in_sizes, int n_in,
                              void* d_out, int out_size, void* d_ws, size_t ws_size,
                              hipStream_t stream) {
    const float* x  = (const float*)d_in[0];
    const int* edges = (const int*)d_in[1];
    const float* W1 = (const float*)d_in[2];
    const float* b1 = (const float*)d_in[3];
    const float* W2 = (const float*)d_in[4];
    const float* b2 = (const float*)d_in[5];
    const float* Wc = (const float*)d_in[6];
    const float* bc = (const float*)d_in[7];
    const float* We = (const float*)d_in[8];
    const float* be = (const float*)d_in[9];

    const int N = in_sizes[0] / 256;   // 100000
    const int E = in_sizes[1] / 2;     // 1600000
    const int* esrc = edges;
    const int* edst = edges + E;

    char* ws = (char*)d_ws;
    size_t off = 0;
    auto alloc = [&](size_t bytes) -> void* {
        void* p = ws + off;
        off += (bytes + 255) & ~(size_t)255;
        return p;
    };
    int*   deg     = (int*)alloc((size_t)N * 4);
    int*   cursor  = (int*)alloc((size_t)N * 4);
    int*   row_ptr = (int*)alloc((size_t)(N + 1) * 4);
    float* dinv    = (float*)alloc((size_t)N * 4);
    int*   bs      = (int*)alloc(4096 * 4);
    int*   csr_src = (int*)alloc((size_t)E * 4);
    float* P       = (float*)alloc((size_t)N * 128 * 4);
    float* Q       = (float*)alloc((size_t)N * 128 * 4);
    float* zA      = (float*)alloc((size_t)N * 64 * 4);
    float* zB      = (float*)alloc((size_t)N * 64 * 4);
    float* evs     = (float*)alloc((size_t)N * 64 * 4);
    float* ev      = (float*)d_out;  // lives in d_out until final log_softmax

    const int nbN = (N + 255) / 256;
    const int nbE = (E + 255) / 256;
    const int nbP = (N + 3) / 4;     // wave-per-node kernels

    // --- CSR build ---
    k_init<<<nbN, 256, 0, stream>>>(deg, cursor, N);
    k_count<<<nbE, 256, 0, stream>>>(edst, deg, E);
    k_scanA<<<nbN, 256, 0, stream>>>(deg, bs, N);
    k_scanB<<<1, 512, 0, stream>>>(bs, nbN);
    k_scanC<<<nbN, 256, 0, stream>>>(deg, bs, row_ptr, dinv, N);
    k_fill<<<nbE, 256, 0, stream>>>(esrc, edst, row_ptr, cursor, csr_src, E);

    // --- GCN layer 1 ---
    k_gemm128<256><<<N / 16, 256, 0, stream>>>(x, W1, dinv, P);
    k_prop2<128, 0><<<nbP, 256, 0, stream>>>(P, row_ptr, csr_src, dinv, b1, nullptr, Q, N);

    // --- GCN layer 2 ---
    k_gemm128<128><<<N / 16, 256, 0, stream>>>(Q, W2, dinv, P);
    k_prop2<128, 0><<<nbP, 256, 0, stream>>>(P, row_ptr, csr_src, dinv, b2, nullptr, Q, N);

    // --- classifier: ev (+ scaled evs) ---
    k_classifier<<<N / 16, 256, 0, stream>>>(Q, Wc, bc, We, be, dinv, ev, evs, N);

    // --- APPNP: 9 scaled iterations + 1 final unscaling iteration ---
    const float* zin = evs;
    float* zout;
    for (int it = 0; it < 9; ++it) {
        zout = (it % 2 == 0) ? zA : zB;
        k_prop2<64, 1><<<nbP, 256, 0, stream>>>(zin, row_ptr, csr_src, dinv, nullptr, evs, zout, N);
        zin = zout;
    }
    // final iteration: unscaled output into zB (zin == zA after 9 iters)
    k_prop2<64, 2><<<nbP, 256, 0, stream>>>(zin, row_ptr, csr_src, dinv, nullptr, ev, zB, N);

    // --- log_softmax -> d_out ---
    k_logsoftmax<<<nbP, 256, 0, stream>>>(zB, (float*)d_out, N);
}

// Round 3
// 1290.368 us; speedup vs baseline: 2.1609x; 1.2469x over previous
//
#include <hip/hip_runtime.h>
#include <hip/hip_fp16.h>

// ---------------------------------------------------------------------------
// GPN_GCN: GCNConv x2 -> classifier -> APPNP(10) -> log_softmax
// CSR per launch; props are wave-per-node gathers over fp16 tables (halved
// bytes/edge vs fp32; fp32 accumulate). GEMMs: 2-col x 8-row register
// blocking so LDS reads amortize over 2x FMAs.
// ---------------------------------------------------------------------------

struct __align__(16) half8 { __half2 h[4]; };

__global__ __launch_bounds__(256) void k_init(int* deg, int* cursor, int N) {
    int i = blockIdx.x * 256 + threadIdx.x;
    if (i < N) { deg[i] = 1; cursor[i] = 0; }  // deg=1 accounts for self-loop
}

__global__ __launch_bounds__(256) void k_count(const int* __restrict__ dst, int* deg, int E) {
    int e = blockIdx.x * 256 + threadIdx.x;
    if (e < E) atomicAdd(&deg[dst[e]], 1);
}

__global__ __launch_bounds__(256) void k_scanA(const int* __restrict__ deg, int* bs, int N) {
    __shared__ int s[256];
    int t = threadIdx.x;
    int i = blockIdx.x * 256 + t;
    int c = (i < N) ? (deg[i] - 1) : 0;
    s[t] = c; __syncthreads();
    for (int o = 128; o > 0; o >>= 1) {
        if (t < o) s[t] += s[t + o];
        __syncthreads();
    }
    if (t == 0) bs[blockIdx.x] = s[0];
}

__global__ __launch_bounds__(512) void k_scanB(int* bs, int NB) {
    __shared__ int s[512];
    int t = threadIdx.x;
    int v = (t < NB) ? bs[t] : 0;
    s[t] = v; __syncthreads();
    for (int o = 1; o < 512; o <<= 1) {
        int u = (t >= o) ? s[t - o] : 0;
        __syncthreads();
        s[t] += u;
        __syncthreads();
    }
    if (t < NB) bs[t] = s[t] - v;  // exclusive
}

__global__ __launch_bounds__(256) void k_scanC(const int* __restrict__ deg, const int* __restrict__ bs,
                                               int* row_ptr, float* dinv, int N) {
    __shared__ int s[256];
    int t = threadIdx.x;
    int i = blockIdx.x * 256 + t;
    int c = (i < N) ? (deg[i] - 1) : 0;
    s[t] = c; __syncthreads();
    for (int o = 1; o < 256; o <<= 1) {
        int u = (t >= o) ? s[t - o] : 0;
        __syncthreads();
        s[t] += u;
        __syncthreads();
    }
    if (i < N) {
        int off = bs[blockIdx.x];
        row_ptr[i] = off + s[t] - c;          // exclusive
        dinv[i] = rsqrtf((float)deg[i]);
        if (i == N - 1) row_ptr[N] = off + s[t];
    }
}

__global__ __launch_bounds__(256) void k_fill(const int* __restrict__ src, const int* __restrict__ dst,
                                              const int* __restrict__ row_ptr, int* cursor,
                                              int* csr_src, int E) {
    int e = blockIdx.x * 256 + threadIdx.x;
    if (e < E) {
        int d = dst[e];
        int pos = row_ptr[d] + atomicAdd(&cursor[d], 1);
        csr_src[pos] = src[e];
    }
}

// Y[M,128] = fp16( dinv[row] * (X[M,K] @ W[K,128]) ).  32 rows/block,
// thread = 2 cols x 8 rows (16 acc): 8 LDS b128 reads feed 64 FMAs per chunk.
template <int K>
__global__ __launch_bounds__(256) void k_gemm128h(const float* __restrict__ X,
                                                  const float* __restrict__ W,
                                                  const float* __restrict__ dinv,
                                                  __half* __restrict__ Y) {
    __shared__ float xs[32 * K];
    int tid = threadIdx.x;
    long rowBase = (long)blockIdx.x * 32;

    const float4* xg = (const float4*)(X + rowBase * K);
    float4* xs4 = (float4*)xs;
    for (int i = tid; i < 32 * K / 4; i += 256) xs4[i] = xg[i];
    __syncthreads();

    int col = tid & 63;          // handles col and col+64
    int r0 = (tid >> 6) * 8;     // 8 rows
    float acc0[8], acc1[8];
#pragma unroll
    for (int r = 0; r < 8; r++) { acc0[r] = 0.f; acc1[r] = 0.f; }

    for (int k = 0; k < K; k += 4) {
        float wa0 = W[(k + 0) * 128 + col], wb0 = W[(k + 0) * 128 + col + 64];
        float wa1 = W[(k + 1) * 128 + col], wb1 = W[(k + 1) * 128 + col + 64];
        float wa2 = W[(k + 2) * 128 + col], wb2 = W[(k + 2) * 128 + col + 64];
        float wa3 = W[(k + 3) * 128 + col], wb3 = W[(k + 3) * 128 + col + 64];
#pragma unroll
        for (int r = 0; r < 8; r++) {
            const float4 xv = *(const float4*)&xs[(r0 + r) * K + k];
            acc0[r] += xv.x * wa0 + xv.y * wa1 + xv.z * wa2 + xv.w * wa3;
            acc1[r] += xv.x * wb0 + xv.y * wb1 + xv.z * wb2 + xv.w * wb3;
        }
    }
#pragma unroll
    for (int r = 0; r < 8; r++) {
        long row = rowBase + r0 + r;
        float d = dinv[row];
        Y[row * 128 + col]      = __float2half(acc0[r] * d);
        Y[row * 128 + col + 64] = __float2half(acc1[r] * d);
    }
}

// Wave-per-node gather propagation over fp16 scaled table tab = dinv (.) h.
// A = sum_{src in nbr(i)} tab[src] + tab[i]   (self loop folded in)
// MODE 0 (GCN):         out(f32) = relu(di*A + bias)
// MODE 1 (APPNP inner): out(f16) = 0.9*di^2*A + 0.1*evs[i]   (scaled space)
// MODE 2 (APPNP final): out(f32) = 0.9*di*A  + 0.1*ev[i]
template <int F, int MODE>
__global__ __launch_bounds__(256) void k_prop2(const __half* __restrict__ tab,
                                               const int* __restrict__ row_ptr,
                                               const int* __restrict__ csr_src,
                                               const float* __restrict__ dinv,
                                               const float* __restrict__ bias,
                                               const void* __restrict__ evx,
                                               void* __restrict__ out, int N) {
    constexpr int LPE = F / 8;    // lanes per edge-slot (half8 = 8 feats each)
    constexpr int S = 64 / LPE;   // edge slots per wave
    int wave = threadIdx.x >> 6;
    int lane = threadIdx.x & 63;
    int node = blockIdx.x * 4 + wave;
    if (node >= N) return;
    int slot = lane / LPE;
    int fl = lane % LPE;          // features 8*fl .. 8*fl+7
    int s = row_ptr[node], e = row_ptr[node + 1];

    float acc[8], accB[8];
#pragma unroll
    for (int q = 0; q < 8; q++) { acc[q] = 0.f; accB[q] = 0.f; }

    int j = s + slot;
    for (; j + S < e; j += 2 * S) {
        const half8 a = *(const half8*)&tab[(long)csr_src[j] * F + 8 * fl];
        const half8 b = *(const half8*)&tab[(long)csr_src[j + S] * F + 8 * fl];
#pragma unroll
        for (int q = 0; q < 4; q++) {
            float2 fa = __half22float2(a.h[q]);
            float2 fb = __half22float2(b.h[q]);
            acc[2 * q] += fa.x; acc[2 * q + 1] += fa.y;
            accB[2 * q] += fb.x; accB[2 * q + 1] += fb.y;
        }
    }
    if (j < e) {
        const half8 a = *(const half8*)&tab[(long)csr_src[j] * F + 8 * fl];
#pragma unroll
        for (int q = 0; q < 4; q++) {
            float2 fa = __half22float2(a.h[q]);
            acc[2 * q] += fa.x; acc[2 * q + 1] += fa.y;
        }
    }
    if (slot == 0) {  // self loop
        const half8 a = *(const half8*)&tab[(long)node * F + 8 * fl];
#pragma unroll
        for (int q = 0; q < 4; q++) {
            float2 fa = __half22float2(a.h[q]);
            acc[2 * q] += fa.x; acc[2 * q + 1] += fa.y;
        }
    }
#pragma unroll
    for (int q = 0; q < 8; q++) acc[q] += accB[q];

#pragma unroll
    for (int off = LPE; off < 64; off <<= 1) {
#pragma unroll
        for (int q = 0; q < 8; q++) acc[q] += __shfl_xor(acc[q], off, 64);
    }

    if (slot == 0) {
        float di = dinv[node];
        if (MODE == 0) {
            const float4 b0 = *(const float4*)&bias[8 * fl];
            const float4 b1 = *(const float4*)&bias[8 * fl + 4];
            float* o = (float*)out + (long)node * F + 8 * fl;
            float4 v0, v1;
            v0.x = fmaxf(di * acc[0] + b0.x, 0.f);
            v0.y = fmaxf(di * acc[1] + b0.y, 0.f);
            v0.z = fmaxf(di * acc[2] + b0.z, 0.f);
            v0.w = fmaxf(di * acc[3] + b0.w, 0.f);
            v1.x = fmaxf(di * acc[4] + b1.x, 0.f);
            v1.y = fmaxf(di * acc[5] + b1.y, 0.f);
            v1.z = fmaxf(di * acc[6] + b1.z, 0.f);
            v1.w = fmaxf(di * acc[7] + b1.w, 0.f);
            *(float4*)o = v0;
            *(float4*)(o + 4) = v1;
        } else if (MODE == 1) {
            float d2 = 0.9f * di * di;
            const half8 eh = *(const half8*)&((const __half*)evx)[(long)node * F + 8 * fl];
            half8 ov;
#pragma unroll
            for (int q = 0; q < 4; q++) {
                float2 ef = __half22float2(eh.h[q]);
                float vx = d2 * acc[2 * q] + 0.1f * ef.x;
                float vy = d2 * acc[2 * q + 1] + 0.1f * ef.y;
                ov.h[q] = __floats2half2_rn(vx, vy);
            }
            *(half8*)&((__half*)out)[(long)node * F + 8 * fl] = ov;
        } else {
            float d1 = 0.9f * di;
            const float* ef = (const float*)evx + (long)node * F + 8 * fl;
            float* o = (float*)out + (long)node * F + 8 * fl;
            const float4 e0 = *(const float4*)ef;
            const float4 e1 = *(const float4*)(ef + 4);
            float4 v0, v1;
            v0.x = d1 * acc[0] + 0.1f * e0.x;
            v0.y = d1 * acc[1] + 0.1f * e0.y;
            v0.z = d1 * acc[2] + 0.1f * e0.z;
            v0.w = d1 * acc[3] + 0.1f * e0.w;
            v1.x = d1 * acc[4] + 0.1f * e1.x;
            v1.y = d1 * acc[5] + 0.1f * e1.y;
            v1.z = d1 * acc[6] + 0.1f * e1.z;
            v1.w = d1 * acc[7] + 0.1f * e1.w;
            *(float4*)o = v0;
            *(float4*)(o + 4) = v1;
        }
    }
}

// ev(f32) = relu((H@Wc + bc)@We + be); also evs(f16) = dinv (.) ev.
__global__ __launch_bounds__(256) void k_classifier(const float* __restrict__ H,
                                                    const float* __restrict__ Wc,
                                                    const float* __restrict__ bc,
                                                    const float* __restrict__ We,
                                                    const float* __restrict__ be,
                                                    const float* __restrict__ dinv,
                                                    float* __restrict__ ev,
                                                    __half* __restrict__ evs, int N) {
    __shared__ float sWc[128 * 64];
    __shared__ float sWe[64 * 64];
    __shared__ float sH[16 * 128];
    __shared__ float sL[16 * 64];
    __shared__ float sbc[64], sbe[64];
    int tid = threadIdx.x;
    long nodeBase = (long)blockIdx.x * 16;

    {
        float4* p = (float4*)sWc; const float4* g = (const float4*)Wc;
        for (int i = tid; i < 128 * 64 / 4; i += 256) p[i] = g[i];
        p = (float4*)sWe; g = (const float4*)We;
        for (int i = tid; i < 64 * 64 / 4; i += 256) p[i] = g[i];
        p = (float4*)sH; g = (const float4*)(H + nodeBase * 128);
        for (int i = tid; i < 16 * 128 / 4; i += 256) p[i] = g[i];
        if (tid < 64) { sbc[tid] = bc[tid]; sbe[tid] = be[tid]; }
    }
    __syncthreads();

    int c = tid & 63, grp = tid >> 6;
    for (int nl = grp; nl < 16; nl += 4) {
        float l = sbc[c];
#pragma unroll 4
        for (int k = 0; k < 128; k++) l += sH[nl * 128 + k] * sWc[k * 64 + c];
        sL[nl * 64 + c] = l;
    }
    __syncthreads();
    for (int nl = grp; nl < 16; nl += 4) {
        float v = sbe[c];
#pragma unroll 4
        for (int j = 0; j < 64; j++) v += sL[nl * 64 + j] * sWe[j * 64 + c];
        v = fmaxf(v, 0.f);
        long node = nodeBase + nl;
        ev[node * 64 + c] = v;
        evs[node * 64 + c] = __float2half(v * dinv[node]);
    }
}

__global__ __launch_bounds__(256) void k_logsoftmax(const float* __restrict__ Z,
                                                    float* __restrict__ out, int N) {
    int node = blockIdx.x * 4 + (threadIdx.x >> 6);
    int c = threadIdx.x & 63;
    if (node >= N) return;
    float v = Z[(long)node * 64 + c];
    float m = v;
    for (int o = 32; o > 0; o >>= 1) m = fmaxf(m, __shfl_xor(m, o, 64));
    float ex = __expf(v - m);
    float ssum = ex;
    for (int o = 32; o > 0; o >>= 1) ssum += __shfl_xor(ssum, o, 64);
    out[(long)node * 64 + c] = v - m - __logf(ssum);
}

extern "C" void kernel_launch(void* const* d_in, const int* in_sizes, int n_in,
                              void* d_out, int out_size, void* d_ws, size_t ws_size,
                              hipStream_t stream) {
    const float* x  = (const float*)d_in[0];
    const int* edges = (const int*)d_in[1];
    const float* W1 = (const float*)d_in[2];
    const float* b1 = (const float*)d_in[3];
    const float* W2 = (const float*)d_in[4];
    const float* b2 = (const float*)d_in[5];
    const float* Wc = (const float*)d_in[6];
    const float* bc = (const float*)d_in[7];
    const float* We = (const float*)d_in[8];
    const float* be = (const float*)d_in[9];

    const int N = in_sizes[0] / 256;   // 100000
    const int E = in_sizes[1] / 2;     // 1600000
    const int* esrc = edges;
    const int* edst = edges + E;

    char* ws = (char*)d_ws;
    size_t off = 0;
    auto alloc = [&](size_t bytes) -> void* {
        void* p = ws + off;
        off += (bytes + 255) & ~(size_t)255;
        return p;
    };
    int*    deg     = (int*)alloc((size_t)N * 4);
    int*    cursor  = (int*)alloc((size_t)N * 4);
    int*    row_ptr = (int*)alloc((size_t)(N + 1) * 4);
    float*  dinv    = (float*)alloc((size_t)N * 4);
    int*    bs      = (int*)alloc(4096 * 4);
    int*    csr_src = (int*)alloc((size_t)E * 4);
    __half* P       = (__half*)alloc((size_t)N * 128 * 2);  // fp16 scaled table
    float*  Q       = (float*)alloc((size_t)N * 128 * 4);
    __half* zA      = (__half*)alloc((size_t)N * 64 * 2);
    __half* zB      = (__half*)alloc((size_t)N * 64 * 2);
    __half* evs     = (__half*)alloc((size_t)N * 64 * 2);
    float*  zF      = (float*)alloc((size_t)N * 64 * 4);
    float*  ev      = (float*)d_out;  // lives in d_out until final log_softmax

    const int nbN = (N + 255) / 256;
    const int nbE = (E + 255) / 256;
    const int nbP = (N + 3) / 4;     // wave-per-node kernels

    // --- CSR build ---
    k_init<<<nbN, 256, 0, stream>>>(deg, cursor, N);
    k_count<<<nbE, 256, 0, stream>>>(edst, deg, E);
    k_scanA<<<nbN, 256, 0, stream>>>(deg, bs, N);
    k_scanB<<<1, 512, 0, stream>>>(bs, nbN);
    k_scanC<<<nbN, 256, 0, stream>>>(deg, bs, row_ptr, dinv, N);
    k_fill<<<nbE, 256, 0, stream>>>(esrc, edst, row_ptr, cursor, csr_src, E);

    // --- GCN layer 1 ---
    k_gemm128h<256><<<N / 32, 256, 0, stream>>>(x, W1, dinv, P);
    k_prop2<128, 0><<<nbP, 256, 0, stream>>>(P, row_ptr, csr_src, dinv, b1, nullptr, Q, N);

    // --- GCN layer 2 ---
    k_gemm128h<128><<<N / 32, 256, 0, stream>>>(Q, W2, dinv, P);
    k_prop2<128, 0><<<nbP, 256, 0, stream>>>(P, row_ptr, csr_src, dinv, b2, nullptr, Q, N);

    // --- classifier: ev (f32, d_out) + evs (f16 scaled) ---
    k_classifier<<<N / 16, 256, 0, stream>>>(Q, Wc, bc, We, be, dinv, ev, evs, N);

    // --- APPNP: 9 scaled fp16 iterations + 1 final unscaling fp32 iteration ---
    const __half* zin = evs;
    __half* zout;
    for (int it = 0; it < 9; ++it) {
        zout = (it % 2 == 0) ? zA : zB;
        k_prop2<64, 1><<<nbP, 256, 0, stream>>>(zin, row_ptr, csr_src, dinv, nullptr, evs, zout, N);
        zin = zout;
    }
    // final iteration reads zA, mixes fp32 ev, writes fp32 zF
    k_prop2<64, 2><<<nbP, 256, 0, stream>>>(zin, row_ptr, csr_src, dinv, nullptr, ev, zF, N);

    // --- log_softmax -> d_out ---
    k_logsoftmax<<<nbP, 256, 0, stream>>>(zF, (float*)d_out, N);
}

// Round 5
// 1210.655 us; speedup vs baseline: 2.3031x; 1.0658x over previous
//
#include <hip/hip_runtime.h>
#include <hip/hip_fp16.h>

// ---------------------------------------------------------------------------
// GPN_GCN: GCNConv x2 -> fused classifier (Wc@We precomputed: no relu between)
// -> APPNP(10, fp16 scaled tables) -> log_softmax fused into last APPNP step.
// CSR per launch; props are wave-per-node half8 gathers, fp32 accumulate.
// (Resubmission of R4 source — previous bench failed on container infra.)
// ---------------------------------------------------------------------------

struct __align__(16) half8 { __half2 h[4]; };

__global__ __launch_bounds__(256) void k_init(int* deg, int* cursor, int N) {
    int i = blockIdx.x * 256 + threadIdx.x;
    if (i < N) { deg[i] = 1; cursor[i] = 0; }  // deg=1 accounts for self-loop
}

__global__ __launch_bounds__(256) void k_count(const int* __restrict__ dst, int* deg, int E) {
    int e = blockIdx.x * 256 + threadIdx.x;
    if (e < E) atomicAdd(&deg[dst[e]], 1);
}

__global__ __launch_bounds__(256) void k_scanA(const int* __restrict__ deg, int* bs, int N) {
    __shared__ int s[256];
    int t = threadIdx.x;
    int i = blockIdx.x * 256 + t;
    int c = (i < N) ? (deg[i] - 1) : 0;
    s[t] = c; __syncthreads();
    for (int o = 128; o > 0; o >>= 1) {
        if (t < o) s[t] += s[t + o];
        __syncthreads();
    }
    if (t == 0) bs[blockIdx.x] = s[0];
}

__global__ __launch_bounds__(512) void k_scanB(int* bs, int NB) {
    __shared__ int s[512];
    int t = threadIdx.x;
    int v = (t < NB) ? bs[t] : 0;
    s[t] = v; __syncthreads();
    for (int o = 1; o < 512; o <<= 1) {
        int u = (t >= o) ? s[t - o] : 0;
        __syncthreads();
        s[t] += u;
        __syncthreads();
    }
    if (t < NB) bs[t] = s[t] - v;  // exclusive
}

__global__ __launch_bounds__(256) void k_scanC(const int* __restrict__ deg, const int* __restrict__ bs,
                                               int* row_ptr, float* dinv, int N) {
    __shared__ int s[256];
    int t = threadIdx.x;
    int i = blockIdx.x * 256 + t;
    int c = (i < N) ? (deg[i] - 1) : 0;
    s[t] = c; __syncthreads();
    for (int o = 1; o < 256; o <<= 1) {
        int u = (t >= o) ? s[t - o] : 0;
        __syncthreads();
        s[t] += u;
        __syncthreads();
    }
    if (i < N) {
        int off = bs[blockIdx.x];
        row_ptr[i] = off + s[t] - c;          // exclusive
        dinv[i] = rsqrtf((float)deg[i]);
        if (i == N - 1) row_ptr[N] = off + s[t];
    }
}

__global__ __launch_bounds__(256) void k_fill(const int* __restrict__ src, const int* __restrict__ dst,
                                              const int* __restrict__ row_ptr, int* cursor,
                                              int* csr_src, int E) {
    int e = blockIdx.x * 256 + threadIdx.x;
    if (e < E) {
        int d = dst[e];
        int pos = row_ptr[d] + atomicAdd(&cursor[d], 1);
        csr_src[pos] = src[e];
    }
}

// Wf = Wc @ We  [128x64], bf = bc @ We + be  [64]. One block.
__global__ __launch_bounds__(256) void k_fuseW(const float* __restrict__ Wc,
                                               const float* __restrict__ bc,
                                               const float* __restrict__ We,
                                               const float* __restrict__ be,
                                               float* __restrict__ Wf,
                                               float* __restrict__ bf) {
    __shared__ float sWe[64 * 64];
    int tid = threadIdx.x;
    for (int i = tid; i < 64 * 64 / 4; i += 256)
        ((float4*)sWe)[i] = ((const float4*)We)[i];
    __syncthreads();
    for (int idx = tid; idx < 128 * 64; idx += 256) {
        int r = idx >> 6, c = idx & 63;
        float s = 0.f;
#pragma unroll 8
        for (int j = 0; j < 64; j++) s += Wc[r * 64 + j] * sWe[j * 64 + c];
        Wf[idx] = s;
    }
    if (tid < 64) {
        float s = be[tid];
#pragma unroll 8
        for (int j = 0; j < 64; j++) s += bc[j] * sWe[j * 64 + tid];
        bf[tid] = s;
    }
}

// Y[M,128] = fp16( dinv[row] * (X[M,K] @ W[K,128]) ).  32 rows/block,
// thread = 2 cols x 8 rows.
template <int K>
__global__ __launch_bounds__(256) void k_gemm128h(const float* __restrict__ X,
                                                  const float* __restrict__ W,
                                                  const float* __restrict__ dinv,
                                                  __half* __restrict__ Y) {
    __shared__ float xs[32 * K];
    int tid = threadIdx.x;
    long rowBase = (long)blockIdx.x * 32;

    const float4* xg = (const float4*)(X + rowBase * K);
    float4* xs4 = (float4*)xs;
    for (int i = tid; i < 32 * K / 4; i += 256) xs4[i] = xg[i];
    __syncthreads();

    int col = tid & 63;          // handles col and col+64
    int r0 = (tid >> 6) * 8;     // 8 rows
    float acc0[8], acc1[8];
#pragma unroll
    for (int r = 0; r < 8; r++) { acc0[r] = 0.f; acc1[r] = 0.f; }

    for (int k = 0; k < K; k += 4) {
        float wa0 = W[(k + 0) * 128 + col], wb0 = W[(k + 0) * 128 + col + 64];
        float wa1 = W[(k + 1) * 128 + col], wb1 = W[(k + 1) * 128 + col + 64];
        float wa2 = W[(k + 2) * 128 + col], wb2 = W[(k + 2) * 128 + col + 64];
        float wa3 = W[(k + 3) * 128 + col], wb3 = W[(k + 3) * 128 + col + 64];
#pragma unroll
        for (int r = 0; r < 8; r++) {
            const float4 xv = *(const float4*)&xs[(r0 + r) * K + k];
            acc0[r] += xv.x * wa0 + xv.y * wa1 + xv.z * wa2 + xv.w * wa3;
            acc1[r] += xv.x * wb0 + xv.y * wb1 + xv.z * wb2 + xv.w * wb3;
        }
    }
#pragma unroll
    for (int r = 0; r < 8; r++) {
        long row = rowBase + r0 + r;
        float d = dinv[row];
        Y[row * 128 + col]      = __float2half(acc0[r] * d);
        Y[row * 128 + col + 64] = __float2half(acc1[r] * d);
    }
}

// Fused classifier: ev(f32,d_out) = relu(H @ Wf + bf); evs(f16) = dinv (.) ev.
// 32 rows/block, thread = 1 col x 8 rows. Wf streamed from L2.
__global__ __launch_bounds__(256) void k_cls(const float* __restrict__ H,
                                             const float* __restrict__ Wf,
                                             const float* __restrict__ bf,
                                             const float* __restrict__ dinv,
                                             float* __restrict__ ev,
                                             __half* __restrict__ evs, int N) {
    __shared__ float sH[32 * 128];
    int tid = threadIdx.x;
    long rowBase = (long)blockIdx.x * 32;
    const float4* xg = (const float4*)(H + rowBase * 128);
    for (int i = tid; i < 32 * 128 / 4; i += 256) ((float4*)sH)[i] = xg[i];
    __syncthreads();

    int col = tid & 63;
    int r0 = (tid >> 6) * 8;
    float acc[8];
#pragma unroll
    for (int r = 0; r < 8; r++) acc[r] = 0.f;

    for (int k = 0; k < 128; k += 4) {
        float w0 = Wf[(k + 0) * 64 + col];
        float w1 = Wf[(k + 1) * 64 + col];
        float w2 = Wf[(k + 2) * 64 + col];
        float w3 = Wf[(k + 3) * 64 + col];
#pragma unroll
        for (int r = 0; r < 8; r++) {
            const float4 xv = *(const float4*)&sH[(r0 + r) * 128 + k];
            acc[r] += xv.x * w0 + xv.y * w1 + xv.z * w2 + xv.w * w3;
        }
    }
    float b = bf[col];
#pragma unroll
    for (int r = 0; r < 8; r++) {
        long row = rowBase + r0 + r;
        float v = fmaxf(acc[r] + b, 0.f);
        ev[row * 64 + col] = v;
        evs[row * 64 + col] = __float2half(v * dinv[row]);
    }
}

// Wave-per-node gather propagation over fp16 scaled table tab = dinv (.) h.
// A = sum_{src in nbr(i)} tab[src] + tab[i]
// MODE 0 (GCN):         out(f32) = relu(di*A + bias)
// MODE 1 (APPNP inner): out(f16) = 0.9*di^2*A + 0.1*evs[i]   (scaled space)
// MODE 2 (APPNP final): out(f32) = log_softmax(0.9*di*A + 0.1*ev[i])
template <int F, int MODE>
__global__ __launch_bounds__(256) void k_prop2(const __half* __restrict__ tab,
                                               const int* __restrict__ row_ptr,
                                               const int* __restrict__ csr_src,
                                               const float* __restrict__ dinv,
                                               const float* __restrict__ bias,
                                               const void* __restrict__ evx,
                                               void* __restrict__ out, int N) {
    constexpr int LPE = F / 8;    // lanes per edge-slot (half8 = 8 feats each)
    constexpr int S = 64 / LPE;   // edge slots per wave
    int wave = threadIdx.x >> 6;
    int lane = threadIdx.x & 63;
    int node = blockIdx.x * 4 + wave;
    if (node >= N) return;
    int slot = lane / LPE;
    int fl = lane % LPE;          // features 8*fl .. 8*fl+7
    int s = row_ptr[node], e = row_ptr[node + 1];

    float acc[8], accB[8];
#pragma unroll
    for (int q = 0; q < 8; q++) { acc[q] = 0.f; accB[q] = 0.f; }

    int j = s + slot;
    for (; j + S < e; j += 2 * S) {
        const half8 a = *(const half8*)&tab[(long)csr_src[j] * F + 8 * fl];
        const half8 b = *(const half8*)&tab[(long)csr_src[j + S] * F + 8 * fl];
#pragma unroll
        for (int q = 0; q < 4; q++) {
            float2 fa = __half22float2(a.h[q]);
            float2 fb = __half22float2(b.h[q]);
            acc[2 * q] += fa.x; acc[2 * q + 1] += fa.y;
            accB[2 * q] += fb.x; accB[2 * q + 1] += fb.y;
        }
    }
    if (j < e) {
        const half8 a = *(const half8*)&tab[(long)csr_src[j] * F + 8 * fl];
#pragma unroll
        for (int q = 0; q < 4; q++) {
            float2 fa = __half22float2(a.h[q]);
            acc[2 * q] += fa.x; acc[2 * q + 1] += fa.y;
        }
    }
    if (slot == 0) {  // self loop
        const half8 a = *(const half8*)&tab[(long)node * F + 8 * fl];
#pragma unroll
        for (int q = 0; q < 4; q++) {
            float2 fa = __half22float2(a.h[q]);
            acc[2 * q] += fa.x; acc[2 * q + 1] += fa.y;
        }
    }
#pragma unroll
    for (int q = 0; q < 8; q++) acc[q] += accB[q];

#pragma unroll
    for (int off = LPE; off < 64; off <<= 1) {
#pragma unroll
        for (int q = 0; q < 8; q++) acc[q] += __shfl_xor(acc[q], off, 64);
    }

    if (slot == 0) {
        float di = dinv[node];
        if (MODE == 0) {
            const float4 b0 = *(const float4*)&bias[8 * fl];
            const float4 b1 = *(const float4*)&bias[8 * fl + 4];
            float* o = (float*)out + (long)node * F + 8 * fl;
            float4 v0, v1;
            v0.x = fmaxf(di * acc[0] + b0.x, 0.f);
            v0.y = fmaxf(di * acc[1] + b0.y, 0.f);
            v0.z = fmaxf(di * acc[2] + b0.z, 0.f);
            v0.w = fmaxf(di * acc[3] + b0.w, 0.f);
            v1.x = fmaxf(di * acc[4] + b1.x, 0.f);
            v1.y = fmaxf(di * acc[5] + b1.y, 0.f);
            v1.z = fmaxf(di * acc[6] + b1.z, 0.f);
            v1.w = fmaxf(di * acc[7] + b1.w, 0.f);
            *(float4*)o = v0;
            *(float4*)(o + 4) = v1;
        } else if (MODE == 1) {
            float d2 = 0.9f * di * di;
            const half8 eh = *(const half8*)&((const __half*)evx)[(long)node * F + 8 * fl];
            half8 ov;
#pragma unroll
            for (int q = 0; q < 4; q++) {
                float2 ef = __half22float2(eh.h[q]);
                float vx = d2 * acc[2 * q] + 0.1f * ef.x;
                float vy = d2 * acc[2 * q + 1] + 0.1f * ef.y;
                ov.h[q] = __floats2half2_rn(vx, vy);
            }
            *(half8*)&((__half*)out)[(long)node * F + 8 * fl] = ov;
        } else {
            // final APPNP step fused with log_softmax (F==64: lanes 0..7
            // of each wave hold the full 64-class row, 8 classes each)
            float d1 = 0.9f * di;
            const float* ef = (const float*)evx + (long)node * F + 8 * fl;
            const float4 e0 = *(const float4*)ef;
            const float4 e1 = *(const float4*)(ef + 4);
            float v[8];
            v[0] = d1 * acc[0] + 0.1f * e0.x;
            v[1] = d1 * acc[1] + 0.1f * e0.y;
            v[2] = d1 * acc[2] + 0.1f * e0.z;
            v[3] = d1 * acc[3] + 0.1f * e0.w;
            v[4] = d1 * acc[4] + 0.1f * e1.x;
            v[5] = d1 * acc[5] + 0.1f * e1.y;
            v[6] = d1 * acc[6] + 0.1f * e1.z;
            v[7] = d1 * acc[7] + 0.1f * e1.w;
            float m = v[0];
#pragma unroll
            for (int q = 1; q < 8; q++) m = fmaxf(m, v[q]);
#pragma unroll
            for (int off = 1; off < LPE; off <<= 1) m = fmaxf(m, __shfl_xor(m, off, 64));
            float ssum = 0.f;
#pragma unroll
            for (int q = 0; q < 8; q++) ssum += __expf(v[q] - m);
#pragma unroll
            for (int off = 1; off < LPE; off <<= 1) ssum += __shfl_xor(ssum, off, 64);
            float lse = m + __logf(ssum);
            float* o = (float*)out + (long)node * F + 8 * fl;
            float4 v0, v1;
            v0.x = v[0] - lse; v0.y = v[1] - lse; v0.z = v[2] - lse; v0.w = v[3] - lse;
            v1.x = v[4] - lse; v1.y = v[5] - lse; v1.z = v[6] - lse; v1.w = v[7] - lse;
            *(float4*)o = v0;
            *(float4*)(o + 4) = v1;
        }
    }
}

extern "C" void kernel_launch(void* const* d_in, const int* in_sizes, int n_in,
                              void* d_out, int out_size, void* d_ws, size_t ws_size,
                              hipStream_t stream) {
    const float* x  = (const float*)d_in[0];
    const int* edges = (const int*)d_in[1];
    const float* W1 = (const float*)d_in[2];
    const float* b1 = (const float*)d_in[3];
    const float* W2 = (const float*)d_in[4];
    const float* b2 = (const float*)d_in[5];
    const float* Wc = (const float*)d_in[6];
    const float* bc = (const float*)d_in[7];
    const float* We = (const float*)d_in[8];
    const float* be = (const float*)d_in[9];

    const int N = in_sizes[0] / 256;   // 100000
    const int E = in_sizes[1] / 2;     // 1600000
    const int* esrc = edges;
    const int* edst = edges + E;

    char* ws = (char*)d_ws;
    size_t off = 0;
    auto alloc = [&](size_t bytes) -> void* {
        void* p = ws + off;
        off += (bytes + 255) & ~(size_t)255;
        return p;
    };
    int*    deg     = (int*)alloc((size_t)N * 4);
    int*    cursor  = (int*)alloc((size_t)N * 4);
    int*    row_ptr = (int*)alloc((size_t)(N + 1) * 4);
    float*  dinv    = (float*)alloc((size_t)N * 4);
    int*    bs      = (int*)alloc(4096 * 4);
    int*    csr_src = (int*)alloc((size_t)E * 4);
    __half* P       = (__half*)alloc((size_t)N * 128 * 2);  // fp16 scaled table
    float*  Q       = (float*)alloc((size_t)N * 128 * 4);
    __half* zA      = (__half*)alloc((size_t)N * 64 * 2);
    __half* zB      = (__half*)alloc((size_t)N * 64 * 2);
    __half* evs     = (__half*)alloc((size_t)N * 64 * 2);
    float*  Wf      = (float*)alloc(128 * 64 * 4);
    float*  bf      = (float*)alloc(64 * 4);
    float*  ev      = (float*)d_out;  // f32 ev lives in d_out until final step

    const int nbN = (N + 255) / 256;
    const int nbE = (E + 255) / 256;
    const int nbP = (N + 3) / 4;     // wave-per-node kernels

    // --- CSR build + weight fusion (independent; fuseW overlaps CSR) ---
    k_init<<<nbN, 256, 0, stream>>>(deg, cursor, N);
    k_count<<<nbE, 256, 0, stream>>>(edst, deg, E);
    k_fuseW<<<1, 256, 0, stream>>>(Wc, bc, We, be, Wf, bf);
    k_scanA<<<nbN, 256, 0, stream>>>(deg, bs, N);
    k_scanB<<<1, 512, 0, stream>>>(bs, nbN);
    k_scanC<<<nbN, 256, 0, stream>>>(deg, bs, row_ptr, dinv, N);
    k_fill<<<nbE, 256, 0, stream>>>(esrc, edst, row_ptr, cursor, csr_src, E);

    // --- GCN layer 1 ---
    k_gemm128h<256><<<N / 32, 256, 0, stream>>>(x, W1, dinv, P);
    k_prop2<128, 0><<<nbP, 256, 0, stream>>>(P, row_ptr, csr_src, dinv, b1, nullptr, Q, N);

    // --- GCN layer 2 ---
    k_gemm128h<128><<<N / 32, 256, 0, stream>>>(Q, W2, dinv, P);
    k_prop2<128, 0><<<nbP, 256, 0, stream>>>(P, row_ptr, csr_src, dinv, b2, nullptr, Q, N);

    // --- fused classifier: ev (f32, d_out) + evs (f16 scaled) ---
    k_cls<<<N / 32, 256, 0, stream>>>(Q, Wf, bf, dinv, ev, evs, N);

    // --- APPNP: 9 scaled fp16 iterations + final step fused w/ log_softmax ---
    const __half* zin = evs;
    __half* zout;
    for (int it = 0; it < 9; ++it) {
        zout = (it % 2 == 0) ? zA : zB;
        k_prop2<64, 1><<<nbP, 256, 0, stream>>>(zin, row_ptr, csr_src, dinv, nullptr, evs, zout, N);
        zin = zout;
    }
    // final: reads zA(f16) + ev(f32,d_out), writes log_softmax rows to d_out
    k_prop2<64, 2><<<nbP, 256, 0, stream>>>(zin, row_ptr, csr_src, dinv, nullptr, ev, (float*)d_out, N);
}

// Round 6
// 1122.260 us; speedup vs baseline: 2.4846x; 1.0788x over previous
//
#include <hip/hip_runtime.h>
#include <hip/hip_fp16.h>

// ---------------------------------------------------------------------------
// GPN_GCN: GCNConv x2 (MFMA f16 GEMMs) -> fused classifier (Wc@We collapsed)
// -> APPNP(10, fp16 scaled tables) -> log_softmax fused into last APPNP step.
// CSR per launch; props are wave-per-node half8 gathers, fp32 accumulate.
// ---------------------------------------------------------------------------

struct __align__(16) half8 { __half2 h[4]; };
typedef _Float16 f16x8 __attribute__((ext_vector_type(8)));
typedef float f32x4 __attribute__((ext_vector_type(4)));

__global__ __launch_bounds__(256) void k_init(int* deg, int* cursor, int N) {
    int i = blockIdx.x * 256 + threadIdx.x;
    if (i < N) { deg[i] = 1; cursor[i] = 0; }  // deg=1 accounts for self-loop
}

__global__ __launch_bounds__(256) void k_count(const int* __restrict__ dst, int* deg, int E) {
    int e = blockIdx.x * 256 + threadIdx.x;
    if (e < E) atomicAdd(&deg[dst[e]], 1);
}

__global__ __launch_bounds__(256) void k_scanA(const int* __restrict__ deg, int* bs, int N) {
    __shared__ int s[256];
    int t = threadIdx.x;
    int i = blockIdx.x * 256 + t;
    int c = (i < N) ? (deg[i] - 1) : 0;
    s[t] = c; __syncthreads();
    for (int o = 128; o > 0; o >>= 1) {
        if (t < o) s[t] += s[t + o];
        __syncthreads();
    }
    if (t == 0) bs[blockIdx.x] = s[0];
}

__global__ __launch_bounds__(512) void k_scanB(int* bs, int NB) {
    __shared__ int s[512];
    int t = threadIdx.x;
    int v = (t < NB) ? bs[t] : 0;
    s[t] = v; __syncthreads();
    for (int o = 1; o < 512; o <<= 1) {
        int u = (t >= o) ? s[t - o] : 0;
        __syncthreads();
        s[t] += u;
        __syncthreads();
    }
    if (t < NB) bs[t] = s[t] - v;  // exclusive
}

__global__ __launch_bounds__(256) void k_scanC(const int* __restrict__ deg, const int* __restrict__ bs,
                                               int* row_ptr, float* dinv, int N) {
    __shared__ int s[256];
    int t = threadIdx.x;
    int i = blockIdx.x * 256 + t;
    int c = (i < N) ? (deg[i] - 1) : 0;
    s[t] = c; __syncthreads();
    for (int o = 1; o < 256; o <<= 1) {
        int u = (t >= o) ? s[t - o] : 0;
        __syncthreads();
        s[t] += u;
        __syncthreads();
    }
    if (i < N) {
        int off = bs[blockIdx.x];
        row_ptr[i] = off + s[t] - c;          // exclusive
        dinv[i] = rsqrtf((float)deg[i]);
        if (i == N - 1) row_ptr[N] = off + s[t];
    }
}

__global__ __launch_bounds__(256) void k_fill(const int* __restrict__ src, const int* __restrict__ dst,
                                              const int* __restrict__ row_ptr, int* cursor,
                                              int* csr_src, int E) {
    int e = blockIdx.x * 256 + threadIdx.x;
    if (e < E) {
        int d = dst[e];
        int pos = row_ptr[d] + atomicAdd(&cursor[d], 1);
        csr_src[pos] = src[e];
    }
}

// Wf = Wc @ We  [128x64], bf = bc @ We + be  [64]. One block.
__global__ __launch_bounds__(256) void k_fuseW(const float* __restrict__ Wc,
                                               const float* __restrict__ bc,
                                               const float* __restrict__ We,
                                               const float* __restrict__ be,
                                               float* __restrict__ Wf,
                                               float* __restrict__ bf) {
    __shared__ float sWe[64 * 64];
    int tid = threadIdx.x;
    for (int i = tid; i < 64 * 64 / 4; i += 256)
        ((float4*)sWe)[i] = ((const float4*)We)[i];
    __syncthreads();
    for (int idx = tid; idx < 128 * 64; idx += 256) {
        int r = idx >> 6, c = idx & 63;
        float s = 0.f;
#pragma unroll 8
        for (int j = 0; j < 64; j++) s += Wc[r * 64 + j] * sWe[j * 64 + c];
        Wf[idx] = s;
    }
    if (tid < 64) {
        float s = be[tid];
#pragma unroll 8
        for (int j = 0; j < 64; j++) s += bc[j] * sWe[j * 64 + tid];
        bf[tid] = s;
    }
}

// Wt[n][k] (f16, [128 x K]) = W[k][n] (f32, [K x 128]) — B-operand layout.
__global__ __launch_bounds__(256) void k_prepW(const float* __restrict__ W,
                                               __half* __restrict__ Wt, int K) {
    int idx = blockIdx.x * 256 + threadIdx.x;
    if (idx < 128 * K) {
        int n = idx / K, k = idx % K;
        Wt[idx] = __float2half(W[k * 128 + n]);
    }
}

// MFMA GEMM: Y[M,128](f16) = dinv[row] * (X[M,K] @ W[K,128]).
// 64 rows/block (4 waves x 16 rows), mfma_f32_16x16x32_f16, K/32 chunks,
// 8 col-tiles. A staged fp32->f16 (or f16 copy) into padded LDS.
// Frag layouts (m89/m120-verified): A[m=lane&15][k=quad*8+j],
// B[n=lane&15][k=quad*8+j], C/D col=lane&15 row=quad*4+reg.
template <int K, bool IN_F16>
__global__ __launch_bounds__(256) void k_mfma_gemm(const void* __restrict__ Xv,
                                                   const __half* __restrict__ Wt,
                                                   const float* __restrict__ dinv,
                                                   __half* __restrict__ Y, int N) {
    constexpr int PAD = 8;               // halves; breaks LDS bank power-of-2 stride
    constexpr int LDK = K + PAD;
    __shared__ __half sA[64 * LDK];
    int tid = threadIdx.x;
    int rowBase = blockIdx.x * 64;

    if (IN_F16) {
        const __half* X = (const __half*)Xv;
        constexpr int C8 = K / 8;
        for (int i = tid; i < 64 * C8; i += 256) {
            int r = i / C8, c8 = i % C8;
            int rg = rowBase + r; if (rg > N - 1) rg = N - 1;
            *(f16x8*)&sA[r * LDK + 8 * c8] = *(const f16x8*)&X[(long)rg * K + 8 * c8];
        }
    } else {
        const float* X = (const float*)Xv;
        constexpr int C4 = K / 4;
        for (int i = tid; i < 64 * C4; i += 256) {
            int r = i / C4, c4 = i % C4;
            int rg = rowBase + r; if (rg > N - 1) rg = N - 1;
            const float4 v = *(const float4*)&X[(long)rg * K + 4 * c4];
            __half2* dst = (__half2*)&sA[r * LDK + 4 * c4];
            dst[0] = __floats2half2_rn(v.x, v.y);
            dst[1] = __floats2half2_rn(v.z, v.w);
        }
    }
    __syncthreads();

    int wave = tid >> 6, lane = tid & 63;
    int m = lane & 15, quad = lane >> 4;   // m doubles as n-within-tile for B
    int rw = wave * 16;

    f32x4 d[8];
#pragma unroll
    for (int ct = 0; ct < 8; ct++) d[ct] = {0.f, 0.f, 0.f, 0.f};

#pragma unroll
    for (int kc = 0; kc < K / 32; kc++) {
        const f16x8 a = *(const f16x8*)&sA[(rw + m) * LDK + kc * 32 + quad * 8];
#pragma unroll
        for (int ct = 0; ct < 8; ct++) {
            const f16x8 b = *(const f16x8*)&Wt[(long)(ct * 16 + m) * K + kc * 32 + quad * 8];
            d[ct] = __builtin_amdgcn_mfma_f32_16x16x32_f16(a, b, d[ct], 0, 0, 0);
        }
    }

#pragma unroll
    for (int ct = 0; ct < 8; ct++) {
        int col = ct * 16 + m;
#pragma unroll
        for (int reg = 0; reg < 4; reg++) {
            int row = rowBase + rw + quad * 4 + reg;
            if (row < N)
                Y[(long)row * 128 + col] = __float2half(d[ct][reg] * dinv[row]);
        }
    }
}

// Fused classifier: ev(f32,d_out) = relu(H @ Wf + bf); evs(f16) = dinv (.) ev.
__global__ __launch_bounds__(256) void k_cls(const float* __restrict__ H,
                                             const float* __restrict__ Wf,
                                             const float* __restrict__ bf,
                                             const float* __restrict__ dinv,
                                             float* __restrict__ ev,
                                             __half* __restrict__ evs, int N) {
    __shared__ float sH[32 * 128];
    int tid = threadIdx.x;
    long rowBase = (long)blockIdx.x * 32;
    const float4* xg = (const float4*)(H + rowBase * 128);
    for (int i = tid; i < 32 * 128 / 4; i += 256) ((float4*)sH)[i] = xg[i];
    __syncthreads();

    int col = tid & 63;
    int r0 = (tid >> 6) * 8;
    float acc[8];
#pragma unroll
    for (int r = 0; r < 8; r++) acc[r] = 0.f;

    for (int k = 0; k < 128; k += 4) {
        float w0 = Wf[(k + 0) * 64 + col];
        float w1 = Wf[(k + 1) * 64 + col];
        float w2 = Wf[(k + 2) * 64 + col];
        float w3 = Wf[(k + 3) * 64 + col];
#pragma unroll
        for (int r = 0; r < 8; r++) {
            const float4 xv = *(const float4*)&sH[(r0 + r) * 128 + k];
            acc[r] += xv.x * w0 + xv.y * w1 + xv.z * w2 + xv.w * w3;
        }
    }
    float b = bf[col];
#pragma unroll
    for (int r = 0; r < 8; r++) {
        long row = rowBase + r0 + r;
        float v = fmaxf(acc[r] + b, 0.f);
        ev[row * 64 + col] = v;
        evs[row * 64 + col] = __float2half(v * dinv[row]);
    }
}

// Wave-per-node gather propagation over fp16 scaled table tab = dinv (.) h.
// A = sum_{src in nbr(i)} tab[src] + tab[i]
// MODE 0 (GCN):         out(f32) = relu(di*A + bias)
// MODE 1 (APPNP inner): out(f16) = 0.9*di^2*A + 0.1*evs[i]   (scaled space)
// MODE 2 (APPNP final): out(f32) = log_softmax(0.9*di*A + 0.1*ev[i])
// MODE 3 (GCN, f16):    out(f16) = relu(di*A + bias)   (unscaled, GEMM input)
template <int F, int MODE>
__global__ __launch_bounds__(256) void k_prop2(const __half* __restrict__ tab,
                                               const int* __restrict__ row_ptr,
                                               const int* __restrict__ csr_src,
                                               const float* __restrict__ dinv,
                                               const float* __restrict__ bias,
                                               const void* __restrict__ evx,
                                               void* __restrict__ out, int N) {
    constexpr int LPE = F / 8;    // lanes per edge-slot (half8 = 8 feats each)
    constexpr int S = 64 / LPE;   // edge slots per wave
    int wave = threadIdx.x >> 6;
    int lane = threadIdx.x & 63;
    int node = blockIdx.x * 4 + wave;
    if (node >= N) return;
    int slot = lane / LPE;
    int fl = lane % LPE;          // features 8*fl .. 8*fl+7
    int s = row_ptr[node], e = row_ptr[node + 1];

    float acc[8], accB[8];
#pragma unroll
    for (int q = 0; q < 8; q++) { acc[q] = 0.f; accB[q] = 0.f; }

    int j = s + slot;
    for (; j + S < e; j += 2 * S) {
        const half8 a = *(const half8*)&tab[(long)csr_src[j] * F + 8 * fl];
        const half8 b = *(const half8*)&tab[(long)csr_src[j + S] * F + 8 * fl];
#pragma unroll
        for (int q = 0; q < 4; q++) {
            float2 fa = __half22float2(a.h[q]);
            float2 fb = __half22float2(b.h[q]);
            acc[2 * q] += fa.x; acc[2 * q + 1] += fa.y;
            accB[2 * q] += fb.x; accB[2 * q + 1] += fb.y;
        }
    }
    if (j < e) {
        const half8 a = *(const half8*)&tab[(long)csr_src[j] * F + 8 * fl];
#pragma unroll
        for (int q = 0; q < 4; q++) {
            float2 fa = __half22float2(a.h[q]);
            acc[2 * q] += fa.x; acc[2 * q + 1] += fa.y;
        }
    }
    if (slot == 0) {  // self loop
        const half8 a = *(const half8*)&tab[(long)node * F + 8 * fl];
#pragma unroll
        for (int q = 0; q < 4; q++) {
            float2 fa = __half22float2(a.h[q]);
            acc[2 * q] += fa.x; acc[2 * q + 1] += fa.y;
        }
    }
#pragma unroll
    for (int q = 0; q < 8; q++) acc[q] += accB[q];

#pragma unroll
    for (int off = LPE; off < 64; off <<= 1) {
#pragma unroll
        for (int q = 0; q < 8; q++) acc[q] += __shfl_xor(acc[q], off, 64);
    }

    if (slot == 0) {
        float di = dinv[node];
        if (MODE == 0) {
            const float4 b0 = *(const float4*)&bias[8 * fl];
            const float4 b1 = *(const float4*)&bias[8 * fl + 4];
            float* o = (float*)out + (long)node * F + 8 * fl;
            float4 v0, v1;
            v0.x = fmaxf(di * acc[0] + b0.x, 0.f);
            v0.y = fmaxf(di * acc[1] + b0.y, 0.f);
            v0.z = fmaxf(di * acc[2] + b0.z, 0.f);
            v0.w = fmaxf(di * acc[3] + b0.w, 0.f);
            v1.x = fmaxf(di * acc[4] + b1.x, 0.f);
            v1.y = fmaxf(di * acc[5] + b1.y, 0.f);
            v1.z = fmaxf(di * acc[6] + b1.z, 0.f);
            v1.w = fmaxf(di * acc[7] + b1.w, 0.f);
            *(float4*)o = v0;
            *(float4*)(o + 4) = v1;
        } else if (MODE == 3) {
            const float4 b0 = *(const float4*)&bias[8 * fl];
            const float4 b1 = *(const float4*)&bias[8 * fl + 4];
            half8 ov;
            ov.h[0] = __floats2half2_rn(fmaxf(di * acc[0] + b0.x, 0.f),
                                        fmaxf(di * acc[1] + b0.y, 0.f));
            ov.h[1] = __floats2half2_rn(fmaxf(di * acc[2] + b0.z, 0.f),
                                        fmaxf(di * acc[3] + b0.w, 0.f));
            ov.h[2] = __floats2half2_rn(fmaxf(di * acc[4] + b1.x, 0.f),
                                        fmaxf(di * acc[5] + b1.y, 0.f));
            ov.h[3] = __floats2half2_rn(fmaxf(di * acc[6] + b1.z, 0.f),
                                        fmaxf(di * acc[7] + b1.w, 0.f));
            *(half8*)&((__half*)out)[(long)node * F + 8 * fl] = ov;
        } else if (MODE == 1) {
            float d2 = 0.9f * di * di;
            const half8 eh = *(const half8*)&((const __half*)evx)[(long)node * F + 8 * fl];
            half8 ov;
#pragma unroll
            for (int q = 0; q < 4; q++) {
                float2 ef = __half22float2(eh.h[q]);
                float vx = d2 * acc[2 * q] + 0.1f * ef.x;
                float vy = d2 * acc[2 * q + 1] + 0.1f * ef.y;
                ov.h[q] = __floats2half2_rn(vx, vy);
            }
            *(half8*)&((__half*)out)[(long)node * F + 8 * fl] = ov;
        } else {
            // final APPNP step fused with log_softmax (F==64: lanes 0..7
            // of each wave hold the full 64-class row, 8 classes each)
            float d1 = 0.9f * di;
            const float* ef = (const float*)evx + (long)node * F + 8 * fl;
            const float4 e0 = *(const float4*)ef;
            const float4 e1 = *(const float4*)(ef + 4);
            float v[8];
            v[0] = d1 * acc[0] + 0.1f * e0.x;
            v[1] = d1 * acc[1] + 0.1f * e0.y;
            v[2] = d1 * acc[2] + 0.1f * e0.z;
            v[3] = d1 * acc[3] + 0.1f * e0.w;
            v[4] = d1 * acc[4] + 0.1f * e1.x;
            v[5] = d1 * acc[5] + 0.1f * e1.y;
            v[6] = d1 * acc[6] + 0.1f * e1.z;
            v[7] = d1 * acc[7] + 0.1f * e1.w;
            float m = v[0];
#pragma unroll
            for (int q = 1; q < 8; q++) m = fmaxf(m, v[q]);
#pragma unroll
            for (int off = 1; off < LPE; off <<= 1) m = fmaxf(m, __shfl_xor(m, off, 64));
            float ssum = 0.f;
#pragma unroll
            for (int q = 0; q < 8; q++) ssum += __expf(v[q] - m);
#pragma unroll
            for (int off = 1; off < LPE; off <<= 1) ssum += __shfl_xor(ssum, off, 64);
            float lse = m + __logf(ssum);
            float* o = (float*)out + (long)node * F + 8 * fl;
            float4 v0, v1;
            v0.x = v[0] - lse; v0.y = v[1] - lse; v0.z = v[2] - lse; v0.w = v[3] - lse;
            v1.x = v[4] - lse; v1.y = v[5] - lse; v1.z = v[6] - lse; v1.w = v[7] - lse;
            *(float4*)o = v0;
            *(float4*)(o + 4) = v1;
        }
    }
}

extern "C" void kernel_launch(void* const* d_in, const int* in_sizes, int n_in,
                              void* d_out, int out_size, void* d_ws, size_t ws_size,
                              hipStream_t stream) {
    const float* x  = (const float*)d_in[0];
    const int* edges = (const int*)d_in[1];
    const float* W1 = (const float*)d_in[2];
    const float* b1 = (const float*)d_in[3];
    const float* W2 = (const float*)d_in[4];
    const float* b2 = (const float*)d_in[5];
    const float* Wc = (const float*)d_in[6];
    const float* bc = (const float*)d_in[7];
    const float* We = (const float*)d_in[8];
    const float* be = (const float*)d_in[9];

    const int N = in_sizes[0] / 256;   // 100000
    const int E = in_sizes[1] / 2;     // 1600000
    const int* esrc = edges;
    const int* edst = edges + E;

    char* ws = (char*)d_ws;
    size_t off = 0;
    auto alloc = [&](size_t bytes) -> void* {
        void* p = ws + off;
        off += (bytes + 255) & ~(size_t)255;
        return p;
    };
    int*    deg     = (int*)alloc((size_t)N * 4);
    int*    cursor  = (int*)alloc((size_t)N * 4);
    int*    row_ptr = (int*)alloc((size_t)(N + 1) * 4);
    float*  dinv    = (float*)alloc((size_t)N * 4);
    int*    bs      = (int*)alloc(4096 * 4);
    int*    csr_src = (int*)alloc((size_t)E * 4);
    __half* P       = (__half*)alloc((size_t)N * 128 * 2);  // f16 scaled table
    __half* Q16     = (__half*)alloc((size_t)N * 128 * 2);  // f16 layer-2 GEMM input
    float*  Q       = (float*)alloc((size_t)N * 128 * 4);   // f32 classifier input
    __half* zA      = (__half*)alloc((size_t)N * 64 * 2);
    __half* zB      = (__half*)alloc((size_t)N * 64 * 2);
    __half* evs     = (__half*)alloc((size_t)N * 64 * 2);
    float*  Wf      = (float*)alloc(128 * 64 * 4);
    float*  bf      = (float*)alloc(64 * 4);
    __half* W1t     = (__half*)alloc(128 * 256 * 2);
    __half* W2t     = (__half*)alloc(128 * 128 * 2);
    float*  ev      = (float*)d_out;  // f32 ev lives in d_out until final step

    const int nbN = (N + 255) / 256;
    const int nbE = (E + 255) / 256;
    const int nbP = (N + 3) / 4;      // wave-per-node kernels
    const int nbG = (N + 63) / 64;    // MFMA GEMM blocks

    // --- CSR build + weight prep (fuseW/prepW independent of CSR) ---
    k_init<<<nbN, 256, 0, stream>>>(deg, cursor, N);
    k_count<<<nbE, 256, 0, stream>>>(edst, deg, E);
    k_fuseW<<<1, 256, 0, stream>>>(Wc, bc, We, be, Wf, bf);
    k_prepW<<<(128 * 256 + 255) / 256, 256, 0, stream>>>(W1, W1t, 256);
    k_prepW<<<(128 * 128 + 255) / 256, 256, 0, stream>>>(W2, W2t, 128);
    k_scanA<<<nbN, 256, 0, stream>>>(deg, bs, N);
    k_scanB<<<1, 512, 0, stream>>>(bs, nbN);
    k_scanC<<<nbN, 256, 0, stream>>>(deg, bs, row_ptr, dinv, N);
    k_fill<<<nbE, 256, 0, stream>>>(esrc, edst, row_ptr, cursor, csr_src, E);

    // --- GCN layer 1: P = f16(dinv * x@W1) via MFMA; Q16 = f16 relu prop ---
    k_mfma_gemm<256, false><<<nbG, 256, 0, stream>>>(x, W1t, dinv, P, N);
    k_prop2<128, 3><<<nbP, 256, 0, stream>>>(P, row_ptr, csr_src, dinv, b1, nullptr, Q16, N);

    // --- GCN layer 2: P = f16(dinv * Q16@W2) via MFMA; Q = f32 relu prop ---
    k_mfma_gemm<128, true><<<nbG, 256, 0, stream>>>(Q16, W2t, dinv, P, N);
    k_prop2<128, 0><<<nbP, 256, 0, stream>>>(P, row_ptr, csr_src, dinv, b2, nullptr, Q, N);

    // --- fused classifier: ev (f32, d_out) + evs (f16 scaled) ---
    k_cls<<<N / 32, 256, 0, stream>>>(Q, Wf, bf, dinv, ev, evs, N);

    // --- APPNP: 9 scaled f16 iterations + final step fused w/ log_softmax ---
    const __half* zin = evs;
    __half* zout;
    for (int it = 0; it < 9; ++it) {
        zout = (it % 2 == 0) ? zA : zB;
        k_prop2<64, 1><<<nbP, 256, 0, stream>>>(zin, row_ptr, csr_src, dinv, nullptr, evs, zout, N);
        zin = zout;
    }
    // final: reads zA(f16) + ev(f32,d_out), writes log_softmax rows to d_out
    k_prop2<64, 2><<<nbP, 256, 0, stream>>>(zin, row_ptr, csr_src, dinv, nullptr, ev, (float*)d_out, N);
}

// Round 7
// 1113.210 us; speedup vs baseline: 2.5048x; 1.0081x over previous
//
#include <hip/hip_runtime.h>
#include <hip/hip_fp16.h>

// ---------------------------------------------------------------------------
// GPN_GCN: GCNConv x2 (MFMA f16 GEMMs) -> fused classifier (Wc@We collapsed)
// -> APPNP(10, fp16 scaled tables) -> log_softmax fused into last APPNP step.
// CSR per launch; props are wave-per-node half8 gathers, fp32 accumulate.
// GEMM: 32 rows/block, 2x2 waves (16 rows x 4 col-tiles each) for occupancy.
// ---------------------------------------------------------------------------

struct __align__(16) half8 { __half2 h[4]; };
typedef _Float16 f16x8 __attribute__((ext_vector_type(8)));
typedef float f32x4 __attribute__((ext_vector_type(4)));

__global__ __launch_bounds__(256) void k_init(int* deg, int* cursor, int N) {
    int i = blockIdx.x * 256 + threadIdx.x;
    if (i < N) { deg[i] = 1; cursor[i] = 0; }  // deg=1 accounts for self-loop
}

__global__ __launch_bounds__(256) void k_count(const int* __restrict__ dst, int* deg, int E) {
    int e = blockIdx.x * 256 + threadIdx.x;
    if (e < E) atomicAdd(&deg[dst[e]], 1);
}

__global__ __launch_bounds__(256) void k_scanA(const int* __restrict__ deg, int* bs, int N) {
    __shared__ int s[256];
    int t = threadIdx.x;
    int i = blockIdx.x * 256 + t;
    int c = (i < N) ? (deg[i] - 1) : 0;
    s[t] = c; __syncthreads();
    for (int o = 128; o > 0; o >>= 1) {
        if (t < o) s[t] += s[t + o];
        __syncthreads();
    }
    if (t == 0) bs[blockIdx.x] = s[0];
}

__global__ __launch_bounds__(512) void k_scanB(int* bs, int NB) {
    __shared__ int s[512];
    int t = threadIdx.x;
    int v = (t < NB) ? bs[t] : 0;
    s[t] = v; __syncthreads();
    for (int o = 1; o < 512; o <<= 1) {
        int u = (t >= o) ? s[t - o] : 0;
        __syncthreads();
        s[t] += u;
        __syncthreads();
    }
    if (t < NB) bs[t] = s[t] - v;  // exclusive
}

__global__ __launch_bounds__(256) void k_scanC(const int* __restrict__ deg, const int* __restrict__ bs,
                                               int* row_ptr, float* dinv, int N) {
    __shared__ int s[256];
    int t = threadIdx.x;
    int i = blockIdx.x * 256 + t;
    int c = (i < N) ? (deg[i] - 1) : 0;
    s[t] = c; __syncthreads();
    for (int o = 1; o < 256; o <<= 1) {
        int u = (t >= o) ? s[t - o] : 0;
        __syncthreads();
        s[t] += u;
        __syncthreads();
    }
    if (i < N) {
        int off = bs[blockIdx.x];
        row_ptr[i] = off + s[t] - c;          // exclusive
        dinv[i] = rsqrtf((float)deg[i]);
        if (i == N - 1) row_ptr[N] = off + s[t];
    }
}

__global__ __launch_bounds__(256) void k_fill(const int* __restrict__ src, const int* __restrict__ dst,
                                              const int* __restrict__ row_ptr, int* cursor,
                                              int* csr_src, int E) {
    int e = blockIdx.x * 256 + threadIdx.x;
    if (e < E) {
        int d = dst[e];
        int pos = row_ptr[d] + atomicAdd(&cursor[d], 1);
        csr_src[pos] = src[e];
    }
}

// Wf = Wc @ We  [128x64], bf = bc @ We + be  [64]. One block.
__global__ __launch_bounds__(256) void k_fuseW(const float* __restrict__ Wc,
                                               const float* __restrict__ bc,
                                               const float* __restrict__ We,
                                               const float* __restrict__ be,
                                               float* __restrict__ Wf,
                                               float* __restrict__ bf) {
    __shared__ float sWe[64 * 64];
    int tid = threadIdx.x;
    for (int i = tid; i < 64 * 64 / 4; i += 256)
        ((float4*)sWe)[i] = ((const float4*)We)[i];
    __syncthreads();
    for (int idx = tid; idx < 128 * 64; idx += 256) {
        int r = idx >> 6, c = idx & 63;
        float s = 0.f;
#pragma unroll 8
        for (int j = 0; j < 64; j++) s += Wc[r * 64 + j] * sWe[j * 64 + c];
        Wf[idx] = s;
    }
    if (tid < 64) {
        float s = be[tid];
#pragma unroll 8
        for (int j = 0; j < 64; j++) s += bc[j] * sWe[j * 64 + tid];
        bf[tid] = s;
    }
}

// Wt[n][k] (f16, [128 x K]) = W[k][n] (f32, [K x 128]) — B-operand layout.
__global__ __launch_bounds__(256) void k_prepW(const float* __restrict__ W,
                                               __half* __restrict__ Wt, int K) {
    int idx = blockIdx.x * 256 + threadIdx.x;
    if (idx < 128 * K) {
        int n = idx / K, k = idx % K;
        Wt[idx] = __float2half(W[k * 128 + n]);
    }
}

// MFMA GEMM: Y[M,128](f16) = dinv[row] * (X[M,K] @ W[K,128]).
// 32 rows/block, 2x2 wave grid: wave = 16 rows x 4 col-tiles (64 cols).
// mfma_f32_16x16x32_f16; A staged (fp32->f16 or f16 copy) in padded LDS;
// B streamed from L1/L2. Frag layouts (m89/m120-verified):
// A[m=lane&15][k=quad*8+j], B[n=lane&15][k=quad*8+j], C/D col=lane&15,
// row=quad*4+reg.
template <int K, bool IN_F16>
__global__ __launch_bounds__(256) void k_mfma_gemm(const void* __restrict__ Xv,
                                                   const __half* __restrict__ Wt,
                                                   const float* __restrict__ dinv,
                                                   __half* __restrict__ Y, int N) {
    constexpr int PAD = 8;               // halves; breaks LDS bank power-of-2 stride
    constexpr int LDK = K + PAD;
    __shared__ __half sA[32 * LDK];
    int tid = threadIdx.x;
    int rowBase = blockIdx.x * 32;

    if (IN_F16) {
        const __half* X = (const __half*)Xv;
        constexpr int C8 = K / 8;
        for (int i = tid; i < 32 * C8; i += 256) {
            int r = i / C8, c8 = i % C8;
            int rg = rowBase + r; if (rg > N - 1) rg = N - 1;
            *(f16x8*)&sA[r * LDK + 8 * c8] = *(const f16x8*)&X[(long)rg * K + 8 * c8];
        }
    } else {
        const float* X = (const float*)Xv;
        constexpr int C4 = K / 4;
        for (int i = tid; i < 32 * C4; i += 256) {
            int r = i / C4, c4 = i % C4;
            int rg = rowBase + r; if (rg > N - 1) rg = N - 1;
            const float4 v = *(const float4*)&X[(long)rg * K + 4 * c4];
            __half2* dst = (__half2*)&sA[r * LDK + 4 * c4];
            dst[0] = __floats2half2_rn(v.x, v.y);
            dst[1] = __floats2half2_rn(v.z, v.w);
        }
    }
    __syncthreads();

    int wave = tid >> 6, lane = tid & 63;
    int m = lane & 15, quad = lane >> 4;   // m doubles as n-within-tile for B
    int rw = (wave & 1) * 16;              // row half
    int cb = (wave >> 1) * 64;             // col half (4 tiles of 16)

    f32x4 d[4];
#pragma unroll
    for (int ct = 0; ct < 4; ct++) d[ct] = {0.f, 0.f, 0.f, 0.f};

#pragma unroll
    for (int kc = 0; kc < K / 32; kc++) {
        const f16x8 a = *(const f16x8*)&sA[(rw + m) * LDK + kc * 32 + quad * 8];
#pragma unroll
        for (int ct = 0; ct < 4; ct++) {
            const f16x8 b = *(const f16x8*)&Wt[(long)(cb + ct * 16 + m) * K + kc * 32 + quad * 8];
            d[ct] = __builtin_amdgcn_mfma_f32_16x16x32_f16(a, b, d[ct], 0, 0, 0);
        }
    }

#pragma unroll
    for (int ct = 0; ct < 4; ct++) {
        int col = cb + ct * 16 + m;
#pragma unroll
        for (int reg = 0; reg < 4; reg++) {
            int row = rowBase + rw + quad * 4 + reg;
            if (row < N)
                Y[(long)row * 128 + col] = __float2half(d[ct][reg] * dinv[row]);
        }
    }
}

// Fused classifier: ev(f32,d_out) = relu(H @ Wf + bf); evs(f16) = dinv (.) ev.
__global__ __launch_bounds__(256) void k_cls(const float* __restrict__ H,
                                             const float* __restrict__ Wf,
                                             const float* __restrict__ bf,
                                             const float* __restrict__ dinv,
                                             float* __restrict__ ev,
                                             __half* __restrict__ evs, int N) {
    __shared__ float sH[32 * 128];
    int tid = threadIdx.x;
    long rowBase = (long)blockIdx.x * 32;
    const float4* xg = (const float4*)(H + rowBase * 128);
    for (int i = tid; i < 32 * 128 / 4; i += 256) ((float4*)sH)[i] = xg[i];
    __syncthreads();

    int col = tid & 63;
    int r0 = (tid >> 6) * 8;
    float acc[8];
#pragma unroll
    for (int r = 0; r < 8; r++) acc[r] = 0.f;

    for (int k = 0; k < 128; k += 4) {
        float w0 = Wf[(k + 0) * 64 + col];
        float w1 = Wf[(k + 1) * 64 + col];
        float w2 = Wf[(k + 2) * 64 + col];
        float w3 = Wf[(k + 3) * 64 + col];
#pragma unroll
        for (int r = 0; r < 8; r++) {
            const float4 xv = *(const float4*)&sH[(r0 + r) * 128 + k];
            acc[r] += xv.x * w0 + xv.y * w1 + xv.z * w2 + xv.w * w3;
        }
    }
    float b = bf[col];
#pragma unroll
    for (int r = 0; r < 8; r++) {
        long row = rowBase + r0 + r;
        float v = fmaxf(acc[r] + b, 0.f);
        ev[row * 64 + col] = v;
        evs[row * 64 + col] = __float2half(v * dinv[row]);
    }
}

// Wave-per-node gather propagation over fp16 scaled table tab = dinv (.) h.
// A = sum_{src in nbr(i)} tab[src] + tab[i]
// MODE 0 (GCN):         out(f32) = relu(di*A + bias)
// MODE 1 (APPNP inner): out(f16) = 0.9*di^2*A + 0.1*evs[i]   (scaled space)
// MODE 2 (APPNP final): out(f32) = log_softmax(0.9*di*A + 0.1*ev[i])
// MODE 3 (GCN, f16):    out(f16) = relu(di*A + bias)   (unscaled, GEMM input)
template <int F, int MODE>
__global__ __launch_bounds__(256) void k_prop2(const __half* __restrict__ tab,
                                               const int* __restrict__ row_ptr,
                                               const int* __restrict__ csr_src,
                                               const float* __restrict__ dinv,
                                               const float* __restrict__ bias,
                                               const void* __restrict__ evx,
                                               void* __restrict__ out, int N) {
    constexpr int LPE = F / 8;    // lanes per edge-slot (half8 = 8 feats each)
    constexpr int S = 64 / LPE;   // edge slots per wave
    int wave = threadIdx.x >> 6;
    int lane = threadIdx.x & 63;
    int node = blockIdx.x * 4 + wave;
    if (node >= N) return;
    int slot = lane / LPE;
    int fl = lane % LPE;          // features 8*fl .. 8*fl+7
    const int2 se = *(const int2*)&row_ptr[node];
    int s = se.x, e = se.y;

    float acc[8], accB[8];
#pragma unroll
    for (int q = 0; q < 8; q++) { acc[q] = 0.f; accB[q] = 0.f; }

    int j = s + slot;
    for (; j + S < e; j += 2 * S) {
        const half8 a = *(const half8*)&tab[(long)csr_src[j] * F + 8 * fl];
        const half8 b = *(const half8*)&tab[(long)csr_src[j + S] * F + 8 * fl];
#pragma unroll
        for (int q = 0; q < 4; q++) {
            float2 fa = __half22float2(a.h[q]);
            float2 fb = __half22float2(b.h[q]);
            acc[2 * q] += fa.x; acc[2 * q + 1] += fa.y;
            accB[2 * q] += fb.x; accB[2 * q + 1] += fb.y;
        }
    }
    if (j < e) {
        const half8 a = *(const half8*)&tab[(long)csr_src[j] * F + 8 * fl];
#pragma unroll
        for (int q = 0; q < 4; q++) {
            float2 fa = __half22float2(a.h[q]);
            acc[2 * q] += fa.x; acc[2 * q + 1] += fa.y;
        }
    }
    if (slot == 0) {  // self loop
        const half8 a = *(const half8*)&tab[(long)node * F + 8 * fl];
#pragma unroll
        for (int q = 0; q < 4; q++) {
            float2 fa = __half22float2(a.h[q]);
            acc[2 * q] += fa.x; acc[2 * q + 1] += fa.y;
        }
    }
#pragma unroll
    for (int q = 0; q < 8; q++) acc[q] += accB[q];

#pragma unroll
    for (int off = LPE; off < 64; off <<= 1) {
#pragma unroll
        for (int q = 0; q < 8; q++) acc[q] += __shfl_xor(acc[q], off, 64);
    }

    if (slot == 0) {
        float di = dinv[node];
        if (MODE == 0) {
            const float4 b0 = *(const float4*)&bias[8 * fl];
            const float4 b1 = *(const float4*)&bias[8 * fl + 4];
            float* o = (float*)out + (long)node * F + 8 * fl;
            float4 v0, v1;
            v0.x = fmaxf(di * acc[0] + b0.x, 0.f);
            v0.y = fmaxf(di * acc[1] + b0.y, 0.f);
            v0.z = fmaxf(di * acc[2] + b0.z, 0.f);
            v0.w = fmaxf(di * acc[3] + b0.w, 0.f);
            v1.x = fmaxf(di * acc[4] + b1.x, 0.f);
            v1.y = fmaxf(di * acc[5] + b1.y, 0.f);
            v1.z = fmaxf(di * acc[6] + b1.z, 0.f);
            v1.w = fmaxf(di * acc[7] + b1.w, 0.f);
            *(float4*)o = v0;
            *(float4*)(o + 4) = v1;
        } else if (MODE == 3) {
            const float4 b0 = *(const float4*)&bias[8 * fl];
            const float4 b1 = *(const float4*)&bias[8 * fl + 4];
            half8 ov;
            ov.h[0] = __floats2half2_rn(fmaxf(di * acc[0] + b0.x, 0.f),
                                        fmaxf(di * acc[1] + b0.y, 0.f));
            ov.h[1] = __floats2half2_rn(fmaxf(di * acc[2] + b0.z, 0.f),
                                        fmaxf(di * acc[3] + b0.w, 0.f));
            ov.h[2] = __floats2half2_rn(fmaxf(di * acc[4] + b1.x, 0.f),
                                        fmaxf(di * acc[5] + b1.y, 0.f));
            ov.h[3] = __floats2half2_rn(fmaxf(di * acc[6] + b1.z, 0.f),
                                        fmaxf(di * acc[7] + b1.w, 0.f));
            *(half8*)&((__half*)out)[(long)node * F + 8 * fl] = ov;
        } else if (MODE == 1) {
            float d2 = 0.9f * di * di;
            const half8 eh = *(const half8*)&((const __half*)evx)[(long)node * F + 8 * fl];
            half8 ov;
#pragma unroll
            for (int q = 0; q < 4; q++) {
                float2 ef = __half22float2(eh.h[q]);
                float vx = d2 * acc[2 * q] + 0.1f * ef.x;
                float vy = d2 * acc[2 * q + 1] + 0.1f * ef.y;
                ov.h[q] = __floats2half2_rn(vx, vy);
            }
            *(half8*)&((__half*)out)[(long)node * F + 8 * fl] = ov;
        } else {
            // final APPNP step fused with log_softmax (F==64: lanes 0..7
            // of each wave hold the full 64-class row, 8 classes each)
            float d1 = 0.9f * di;
            const float* ef = (const float*)evx + (long)node * F + 8 * fl;
            const float4 e0 = *(const float4*)ef;
            const float4 e1 = *(const float4*)(ef + 4);
            float v[8];
            v[0] = d1 * acc[0] + 0.1f * e0.x;
            v[1] = d1 * acc[1] + 0.1f * e0.y;
            v[2] = d1 * acc[2] + 0.1f * e0.z;
            v[3] = d1 * acc[3] + 0.1f * e0.w;
            v[4] = d1 * acc[4] + 0.1f * e1.x;
            v[5] = d1 * acc[5] + 0.1f * e1.y;
            v[6] = d1 * acc[6] + 0.1f * e1.z;
            v[7] = d1 * acc[7] + 0.1f * e1.w;
            float m = v[0];
#pragma unroll
            for (int q = 1; q < 8; q++) m = fmaxf(m, v[q]);
#pragma unroll
            for (int off = 1; off < LPE; off <<= 1) m = fmaxf(m, __shfl_xor(m, off, 64));
            float ssum = 0.f;
#pragma unroll
            for (int q = 0; q < 8; q++) ssum += __expf(v[q] - m);
#pragma unroll
            for (int off = 1; off < LPE; off <<= 1) ssum += __shfl_xor(ssum, off, 64);
            float lse = m + __logf(ssum);
            float* o = (float*)out + (long)node * F + 8 * fl;
            float4 v0, v1;
            v0.x = v[0] - lse; v0.y = v[1] - lse; v0.z = v[2] - lse; v0.w = v[3] - lse;
            v1.x = v[4] - lse; v1.y = v[5] - lse; v1.z = v[6] - lse; v1.w = v[7] - lse;
            *(float4*)o = v0;
            *(float4*)(o + 4) = v1;
        }
    }
}

extern "C" void kernel_launch(void* const* d_in, const int* in_sizes, int n_in,
                              void* d_out, int out_size, void* d_ws, size_t ws_size,
                              hipStream_t stream) {
    const float* x  = (const float*)d_in[0];
    const int* edges = (const int*)d_in[1];
    const float* W1 = (const float*)d_in[2];
    const float* b1 = (const float*)d_in[3];
    const float* W2 = (const float*)d_in[4];
    const float* b2 = (const float*)d_in[5];
    const float* Wc = (const float*)d_in[6];
    const float* bc = (const float*)d_in[7];
    const float* We = (const float*)d_in[8];
    const float* be = (const float*)d_in[9];

    const int N = in_sizes[0] / 256;   // 100000
    const int E = in_sizes[1] / 2;     // 1600000
    const int* esrc = edges;
    const int* edst = edges + E;

    char* ws = (char*)d_ws;
    size_t off = 0;
    auto alloc = [&](size_t bytes) -> void* {
        void* p = ws + off;
        off += (bytes + 255) & ~(size_t)255;
        return p;
    };
    int*    deg     = (int*)alloc((size_t)N * 4);
    int*    cursor  = (int*)alloc((size_t)N * 4);
    int*    row_ptr = (int*)alloc((size_t)(N + 1) * 4);
    float*  dinv    = (float*)alloc((size_t)N * 4);
    int*    bs      = (int*)alloc(4096 * 4);
    int*    csr_src = (int*)alloc((size_t)E * 4);
    __half* P       = (__half*)alloc((size_t)N * 128 * 2);  // f16 scaled table
    __half* Q16     = (__half*)alloc((size_t)N * 128 * 2);  // f16 layer-2 GEMM input
    float*  Q       = (float*)alloc((size_t)N * 128 * 4);   // f32 classifier input
    __half* zA      = (__half*)alloc((size_t)N * 64 * 2);
    __half* zB      = (__half*)alloc((size_t)N * 64 * 2);
    __half* evs     = (__half*)alloc((size_t)N * 64 * 2);
    float*  Wf      = (float*)alloc(128 * 64 * 4);
    float*  bf      = (float*)alloc(64 * 4);
    __half* W1t     = (__half*)alloc(128 * 256 * 2);
    __half* W2t     = (__half*)alloc(128 * 128 * 2);
    float*  ev      = (float*)d_out;  // f32 ev lives in d_out until final step

    const int nbN = (N + 255) / 256;
    const int nbE = (E + 255) / 256;
    const int nbP = (N + 3) / 4;      // wave-per-node kernels
    const int nbG = (N + 31) / 32;    // MFMA GEMM blocks (32 rows each)

    // --- CSR build + weight prep (fuseW/prepW independent of CSR) ---
    k_init<<<nbN, 256, 0, stream>>>(deg, cursor, N);
    k_count<<<nbE, 256, 0, stream>>>(edst, deg, E);
    k_fuseW<<<1, 256, 0, stream>>>(Wc, bc, We, be, Wf, bf);
    k_prepW<<<(128 * 256 + 255) / 256, 256, 0, stream>>>(W1, W1t, 256);
    k_prepW<<<(128 * 128 + 255) / 256, 256, 0, stream>>>(W2, W2t, 128);
    k_scanA<<<nbN, 256, 0, stream>>>(deg, bs, N);
    k_scanB<<<1, 512, 0, stream>>>(bs, nbN);
    k_scanC<<<nbN, 256, 0, stream>>>(deg, bs, row_ptr, dinv, N);
    k_fill<<<nbE, 256, 0, stream>>>(esrc, edst, row_ptr, cursor, csr_src, E);

    // --- GCN layer 1: P = f16(dinv * x@W1) via MFMA; Q16 = f16 relu prop ---
    k_mfma_gemm<256, false><<<nbG, 256, 0, stream>>>(x, W1t, dinv, P, N);
    k_prop2<128, 3><<<nbP, 256, 0, stream>>>(P, row_ptr, csr_src, dinv, b1, nullptr, Q16, N);

    // --- GCN layer 2: P = f16(dinv * Q16@W2) via MFMA; Q = f32 relu prop ---
    k_mfma_gemm<128, true><<<nbG, 256, 0, stream>>>(Q16, W2t, dinv, P, N);
    k_prop2<128, 0><<<nbP, 256, 0, stream>>>(P, row_ptr, csr_src, dinv, b2, nullptr, Q, N);

    // --- fused classifier: ev (f32, d_out) + evs (f16 scaled) ---
    k_cls<<<N / 32, 256, 0, stream>>>(Q, Wf, bf, dinv, ev, evs, N);

    // --- APPNP: 9 scaled f16 iterations + final step fused w/ log_softmax ---
    const __half* zin = evs;
    __half* zout;
    for (int it = 0; it < 9; ++it) {
        zout = (it % 2 == 0) ? zA : zB;
        k_prop2<64, 1><<<nbP, 256, 0, stream>>>(zin, row_ptr, csr_src, dinv, nullptr, evs, zout, N);
        zin = zout;
    }
    // final: reads zA(f16) + ev(f32,d_out), writes log_softmax rows to d_out
    k_prop2<64, 2><<<nbP, 256, 0, stream>>>(zin, row_ptr, csr_src, dinv, nullptr, ev, (float*)d_out, N);
}

// Round 8
// 1078.594 us; speedup vs baseline: 2.5851x; 1.0321x over previous
//
#include <hip/hip_runtime.h>
#include <hip/hip_fp16.h>

// ---------------------------------------------------------------------------
// GPN_GCN: GCNConv x2 (MFMA f16 GEMMs, B register-resident) -> fused
// classifier (Wc@We collapsed) -> APPNP(10, f16 scaled tables) -> log_softmax
// fused into last APPNP step. CSR per launch (rank trick: no fill atomics);
// props are wave-per-node half8 gathers, fp32 accumulate.
// ---------------------------------------------------------------------------

struct __align__(16) half8 { __half2 h[4]; };
typedef _Float16 f16x8 __attribute__((ext_vector_type(8)));
typedef float f32x4 __attribute__((ext_vector_type(4)));

__global__ __launch_bounds__(256) void k_init(int* deg, int N) {
    int i = blockIdx.x * 256 + threadIdx.x;
    if (i < N) deg[i] = 1;  // deg=1 accounts for self-loop
}

// atomicAdd return value = rank of edge within its dst (starts at 1 since
// deg init = 1 for self-loop) -> rank[e] = old - 1 in [0, deg-2].
__global__ __launch_bounds__(256) void k_count(const int* __restrict__ dst,
                                               int* deg, int* __restrict__ rank, int E) {
    int e = blockIdx.x * 256 + threadIdx.x;
    if (e < E) {
        int r = atomicAdd(&deg[dst[e]], 1);
        rank[e] = r - 1;
    }
}

__global__ __launch_bounds__(256) void k_scanA(const int* __restrict__ deg, int* bs, int N) {
    __shared__ int s[256];
    int t = threadIdx.x;
    int i = blockIdx.x * 256 + t;
    int c = (i < N) ? (deg[i] - 1) : 0;
    s[t] = c; __syncthreads();
    for (int o = 128; o > 0; o >>= 1) {
        if (t < o) s[t] += s[t + o];
        __syncthreads();
    }
    if (t == 0) bs[blockIdx.x] = s[0];
}

__global__ __launch_bounds__(512) void k_scanB(int* bs, int NB) {
    __shared__ int s[512];
    int t = threadIdx.x;
    int v = (t < NB) ? bs[t] : 0;
    s[t] = v; __syncthreads();
    for (int o = 1; o < 512; o <<= 1) {
        int u = (t >= o) ? s[t - o] : 0;
        __syncthreads();
        s[t] += u;
        __syncthreads();
    }
    if (t < NB) bs[t] = s[t] - v;  // exclusive
}

__global__ __launch_bounds__(256) void k_scanC(const int* __restrict__ deg, const int* __restrict__ bs,
                                               int* row_ptr, float* dinv, int N) {
    __shared__ int s[256];
    int t = threadIdx.x;
    int i = blockIdx.x * 256 + t;
    int c = (i < N) ? (deg[i] - 1) : 0;
    s[t] = c; __syncthreads();
    for (int o = 1; o < 256; o <<= 1) {
        int u = (t >= o) ? s[t - o] : 0;
        __syncthreads();
        s[t] += u;
        __syncthreads();
    }
    if (i < N) {
        int off = bs[blockIdx.x];
        row_ptr[i] = off + s[t] - c;          // exclusive
        dinv[i] = rsqrtf((float)deg[i]);
        if (i == N - 1) row_ptr[N] = off + s[t];
    }
}

// Atomic-free fill using precomputed ranks.
__global__ __launch_bounds__(256) void k_fill(const int* __restrict__ src, const int* __restrict__ dst,
                                              const int* __restrict__ row_ptr,
                                              const int* __restrict__ rank,
                                              int* __restrict__ csr_src, int E) {
    int e = blockIdx.x * 256 + threadIdx.x;
    if (e < E) csr_src[row_ptr[dst[e]] + rank[e]] = src[e];
}

// Wf = Wc @ We  [128x64], bf = bc @ We + be  [64]. One block.
__global__ __launch_bounds__(256) void k_fuseW(const float* __restrict__ Wc,
                                               const float* __restrict__ bc,
                                               const float* __restrict__ We,
                                               const float* __restrict__ be,
                                               float* __restrict__ Wf,
                                               float* __restrict__ bf) {
    __shared__ float sWe[64 * 64];
    int tid = threadIdx.x;
    for (int i = tid; i < 64 * 64 / 4; i += 256)
        ((float4*)sWe)[i] = ((const float4*)We)[i];
    __syncthreads();
    for (int idx = tid; idx < 128 * 64; idx += 256) {
        int r = idx >> 6, c = idx & 63;
        float s = 0.f;
#pragma unroll 8
        for (int j = 0; j < 64; j++) s += Wc[r * 64 + j] * sWe[j * 64 + c];
        Wf[idx] = s;
    }
    if (tid < 64) {
        float s = be[tid];
#pragma unroll 8
        for (int j = 0; j < 64; j++) s += bc[j] * sWe[j * 64 + tid];
        bf[tid] = s;
    }
}

// Wt[n][k] (f16, [128 x K]) = W[k][n] (f32, [K x 128]) — B-operand layout.
__global__ __launch_bounds__(256) void k_prepW(const float* __restrict__ W,
                                               __half* __restrict__ Wt, int K) {
    int idx = blockIdx.x * 256 + threadIdx.x;
    if (idx < 128 * K) {
        int n = idx / K, k = idx % K;
        Wt[idx] = __float2half(W[k * 128 + n]);
    }
}

// MFMA GEMM: Y[M,128](f16) = dinv[row] * (X[M,K] @ W[K,128]).
// 32 rows/block, 2x2 wave grid: wave = 16 rows x 4 col-tiles (64 cols).
// ALL B fragments register-resident (K/32 x 4 frags; 128 VGPR at K=256) —
// the K-loop is pure ds_read + MFMA, no in-loop global loads.
// __launch_bounds__(256,2): allow up to 256 VGPR so B stays resident.
// Frag layouts (m89/m120-verified): A[m=lane&15][k=quad*8+j],
// B[n=lane&15][k=quad*8+j], C/D col=lane&15, row=quad*4+reg.
template <int K, bool IN_F16>
__global__ __launch_bounds__(256, 2) void k_mfma_gemm(const void* __restrict__ Xv,
                                                      const __half* __restrict__ Wt,
                                                      const float* __restrict__ dinv,
                                                      __half* __restrict__ Y, int N) {
    constexpr int PAD = 8;               // halves
    constexpr int LDK = K + PAD;
    __shared__ __half sA[32 * LDK];
    int tid = threadIdx.x;
    int rowBase = blockIdx.x * 32;
    int wave = tid >> 6, lane = tid & 63;
    int m = lane & 15, quad = lane >> 4;   // m doubles as n-within-tile for B
    int rw = (wave & 1) * 16;              // row half
    int cb = (wave >> 1) * 64;             // col half (4 tiles of 16)

    // --- B fragments: load all, keep resident ---
    f16x8 bf[K / 32][4];
#pragma unroll
    for (int kc = 0; kc < K / 32; kc++)
#pragma unroll
        for (int ct = 0; ct < 4; ct++)
            bf[kc][ct] = *(const f16x8*)&Wt[(long)(cb + ct * 16 + m) * K + kc * 32 + quad * 8];

    // --- stage A tile to LDS (f32->f16 convert or f16 copy) ---
    if (IN_F16) {
        const __half* X = (const __half*)Xv;
        constexpr int C8 = K / 8;
        for (int i = tid; i < 32 * C8; i += 256) {
            int r = i / C8, c8 = i % C8;
            int rg = rowBase + r; if (rg > N - 1) rg = N - 1;
            *(f16x8*)&sA[r * LDK + 8 * c8] = *(const f16x8*)&X[(long)rg * K + 8 * c8];
        }
    } else {
        const float* X = (const float*)Xv;
        constexpr int C4 = K / 4;
        for (int i = tid; i < 32 * C4; i += 256) {
            int r = i / C4, c4 = i % C4;
            int rg = rowBase + r; if (rg > N - 1) rg = N - 1;
            const float4 v = *(const float4*)&X[(long)rg * K + 4 * c4];
            __half2* dst = (__half2*)&sA[r * LDK + 4 * c4];
            dst[0] = __floats2half2_rn(v.x, v.y);
            dst[1] = __floats2half2_rn(v.z, v.w);
        }
    }
    __syncthreads();

    f32x4 d[4];
#pragma unroll
    for (int ct = 0; ct < 4; ct++) d[ct] = {0.f, 0.f, 0.f, 0.f};

#pragma unroll
    for (int kc = 0; kc < K / 32; kc++) {
        const f16x8 a = *(const f16x8*)&sA[(rw + m) * LDK + kc * 32 + quad * 8];
#pragma unroll
        for (int ct = 0; ct < 4; ct++)
            d[ct] = __builtin_amdgcn_mfma_f32_16x16x32_f16(a, bf[kc][ct], d[ct], 0, 0, 0);
    }

#pragma unroll
    for (int ct = 0; ct < 4; ct++) {
        int col = cb + ct * 16 + m;
#pragma unroll
        for (int reg = 0; reg < 4; reg++) {
            int row = rowBase + rw + quad * 4 + reg;
            if (row < N)
                Y[(long)row * 128 + col] = __float2half(d[ct][reg] * dinv[row]);
        }
    }
}

// Fused classifier (f16 input): ev(f32,d_out) = relu(H @ Wf + bf);
// evs(f16) = dinv (.) ev.
__global__ __launch_bounds__(256) void k_cls(const __half* __restrict__ H,
                                             const float* __restrict__ Wf,
                                             const float* __restrict__ bf,
                                             const float* __restrict__ dinv,
                                             float* __restrict__ ev,
                                             __half* __restrict__ evs, int N) {
    __shared__ __half sH[32 * 128];
    int tid = threadIdx.x;
    long rowBase = (long)blockIdx.x * 32;
    const half8* xg = (const half8*)(H + rowBase * 128);
    for (int i = tid; i < 32 * 128 / 8; i += 256) ((half8*)sH)[i] = xg[i];
    __syncthreads();

    int col = tid & 63;
    int r0 = (tid >> 6) * 8;
    float acc[8];
#pragma unroll
    for (int r = 0; r < 8; r++) acc[r] = 0.f;

    for (int k = 0; k < 128; k += 4) {
        float w0 = Wf[(k + 0) * 64 + col];
        float w1 = Wf[(k + 1) * 64 + col];
        float w2 = Wf[(k + 2) * 64 + col];
        float w3 = Wf[(k + 3) * 64 + col];
#pragma unroll
        for (int r = 0; r < 8; r++) {
            const __half2 h01 = *(const __half2*)&sH[(r0 + r) * 128 + k];
            const __half2 h23 = *(const __half2*)&sH[(r0 + r) * 128 + k + 2];
            float2 f01 = __half22float2(h01);
            float2 f23 = __half22float2(h23);
            acc[r] += f01.x * w0 + f01.y * w1 + f23.x * w2 + f23.y * w3;
        }
    }
    float b = bf[col];
#pragma unroll
    for (int r = 0; r < 8; r++) {
        long row = rowBase + r0 + r;
        float v = fmaxf(acc[r] + b, 0.f);
        ev[row * 64 + col] = v;
        evs[row * 64 + col] = __float2half(v * dinv[row]);
    }
}

// Wave-per-node gather propagation over fp16 scaled table tab = dinv (.) h.
// A = sum_{src in nbr(i)} tab[src] + tab[i]
// MODE 3 (GCN, f16):    out(f16) = relu(di*A + bias)   (unscaled, next input)
// MODE 1 (APPNP inner): out(f16) = 0.9*di^2*A + 0.1*evs[i]   (scaled space)
// MODE 2 (APPNP final): out(f32) = log_softmax(0.9*di*A + 0.1*ev[i])
template <int F, int MODE>
__global__ __launch_bounds__(256) void k_prop2(const __half* __restrict__ tab,
                                               const int* __restrict__ row_ptr,
                                               const int* __restrict__ csr_src,
                                               const float* __restrict__ dinv,
                                               const float* __restrict__ bias,
                                               const void* __restrict__ evx,
                                               void* __restrict__ out, int N) {
    constexpr int LPE = F / 8;    // lanes per edge-slot (half8 = 8 feats each)
    constexpr int S = 64 / LPE;   // edge slots per wave
    int wave = threadIdx.x >> 6;
    int lane = threadIdx.x & 63;
    int node = blockIdx.x * 4 + wave;
    if (node >= N) return;
    int slot = lane / LPE;
    int fl = lane % LPE;          // features 8*fl .. 8*fl+7
    const int2 se = *(const int2*)&row_ptr[node];
    int s = se.x, e = se.y;

    float acc[8], accB[8];
#pragma unroll
    for (int q = 0; q < 8; q++) { acc[q] = 0.f; accB[q] = 0.f; }

    int j = s + slot;
    for (; j + S < e; j += 2 * S) {
        const half8 a = *(const half8*)&tab[(long)csr_src[j] * F + 8 * fl];
        const half8 b = *(const half8*)&tab[(long)csr_src[j + S] * F + 8 * fl];
#pragma unroll
        for (int q = 0; q < 4; q++) {
            float2 fa = __half22float2(a.h[q]);
            float2 fb = __half22float2(b.h[q]);
            acc[2 * q] += fa.x; acc[2 * q + 1] += fa.y;
            accB[2 * q] += fb.x; accB[2 * q + 1] += fb.y;
        }
    }
    if (j < e) {
        const half8 a = *(const half8*)&tab[(long)csr_src[j] * F + 8 * fl];
#pragma unroll
        for (int q = 0; q < 4; q++) {
            float2 fa = __half22float2(a.h[q]);
            acc[2 * q] += fa.x; acc[2 * q + 1] += fa.y;
        }
    }
    if (slot == 0) {  // self loop
        const half8 a = *(const half8*)&tab[(long)node * F + 8 * fl];
#pragma unroll
        for (int q = 0; q < 4; q++) {
            float2 fa = __half22float2(a.h[q]);
            acc[2 * q] += fa.x; acc[2 * q + 1] += fa.y;
        }
    }
#pragma unroll
    for (int q = 0; q < 8; q++) acc[q] += accB[q];

#pragma unroll
    for (int off = LPE; off < 64; off <<= 1) {
#pragma unroll
        for (int q = 0; q < 8; q++) acc[q] += __shfl_xor(acc[q], off, 64);
    }

    if (slot == 0) {
        float di = dinv[node];
        if (MODE == 3) {
            const float4 b0 = *(const float4*)&bias[8 * fl];
            const float4 b1 = *(const float4*)&bias[8 * fl + 4];
            half8 ov;
            ov.h[0] = __floats2half2_rn(fmaxf(di * acc[0] + b0.x, 0.f),
                                        fmaxf(di * acc[1] + b0.y, 0.f));
            ov.h[1] = __floats2half2_rn(fmaxf(di * acc[2] + b0.z, 0.f),
                                        fmaxf(di * acc[3] + b0.w, 0.f));
            ov.h[2] = __floats2half2_rn(fmaxf(di * acc[4] + b1.x, 0.f),
                                        fmaxf(di * acc[5] + b1.y, 0.f));
            ov.h[3] = __floats2half2_rn(fmaxf(di * acc[6] + b1.z, 0.f),
                                        fmaxf(di * acc[7] + b1.w, 0.f));
            *(half8*)&((__half*)out)[(long)node * F + 8 * fl] = ov;
        } else if (MODE == 1) {
            float d2 = 0.9f * di * di;
            const half8 eh = *(const half8*)&((const __half*)evx)[(long)node * F + 8 * fl];
            half8 ov;
#pragma unroll
            for (int q = 0; q < 4; q++) {
                float2 ef = __half22float2(eh.h[q]);
                float vx = d2 * acc[2 * q] + 0.1f * ef.x;
                float vy = d2 * acc[2 * q + 1] + 0.1f * ef.y;
                ov.h[q] = __floats2half2_rn(vx, vy);
            }
            *(half8*)&((__half*)out)[(long)node * F + 8 * fl] = ov;
        } else {
            // final APPNP step fused with log_softmax (F==64: lanes 0..7
            // of each wave hold the full 64-class row, 8 classes each)
            float d1 = 0.9f * di;
            const float* ef = (const float*)evx + (long)node * F + 8 * fl;
            const float4 e0 = *(const float4*)ef;
            const float4 e1 = *(const float4*)(ef + 4);
            float v[8];
            v[0] = d1 * acc[0] + 0.1f * e0.x;
            v[1] = d1 * acc[1] + 0.1f * e0.y;
            v[2] = d1 * acc[2] + 0.1f * e0.z;
            v[3] = d1 * acc[3] + 0.1f * e0.w;
            v[4] = d1 * acc[4] + 0.1f * e1.x;
            v[5] = d1 * acc[5] + 0.1f * e1.y;
            v[6] = d1 * acc[6] + 0.1f * e1.z;
            v[7] = d1 * acc[7] + 0.1f * e1.w;
            float m = v[0];
#pragma unroll
            for (int q = 1; q < 8; q++) m = fmaxf(m, v[q]);
#pragma unroll
            for (int off = 1; off < LPE; off <<= 1) m = fmaxf(m, __shfl_xor(m, off, 64));
            float ssum = 0.f;
#pragma unroll
            for (int q = 0; q < 8; q++) ssum += __expf(v[q] - m);
#pragma unroll
            for (int off = 1; off < LPE; off <<= 1) ssum += __shfl_xor(ssum, off, 64);
            float lse = m + __logf(ssum);
            float* o = (float*)out + (long)node * F + 8 * fl;
            float4 v0, v1;
            v0.x = v[0] - lse; v0.y = v[1] - lse; v0.z = v[2] - lse; v0.w = v[3] - lse;
            v1.x = v[4] - lse; v1.y = v[5] - lse; v1.z = v[6] - lse; v1.w = v[7] - lse;
            *(float4*)o = v0;
            *(float4*)(o + 4) = v1;
        }
    }
}

extern "C" void kernel_launch(void* const* d_in, const int* in_sizes, int n_in,
                              void* d_out, int out_size, void* d_ws, size_t ws_size,
                              hipStream_t stream) {
    const float* x  = (const float*)d_in[0];
    const int* edges = (const int*)d_in[1];
    const float* W1 = (const float*)d_in[2];
    const float* b1 = (const float*)d_in[3];
    const float* W2 = (const float*)d_in[4];
    const float* b2 = (const float*)d_in[5];
    const float* Wc = (const float*)d_in[6];
    const float* bc = (const float*)d_in[7];
    const float* We = (const float*)d_in[8];
    const float* be = (const float*)d_in[9];

    const int N = in_sizes[0] / 256;   // 100000
    const int E = in_sizes[1] / 2;     // 1600000
    const int* esrc = edges;
    const int* edst = edges + E;

    char* ws = (char*)d_ws;
    size_t off = 0;
    auto alloc = [&](size_t bytes) -> void* {
        void* p = ws + off;
        off += (bytes + 255) & ~(size_t)255;
        return p;
    };
    int*    deg     = (int*)alloc((size_t)N * 4);
    int*    row_ptr = (int*)alloc((size_t)(N + 1) * 4);
    float*  dinv    = (float*)alloc((size_t)N * 4);
    int*    bs      = (int*)alloc(4096 * 4);
    int*    rank    = (int*)alloc((size_t)E * 4);
    int*    csr_src = (int*)alloc((size_t)E * 4);
    __half* P       = (__half*)alloc((size_t)N * 128 * 2);  // f16 table A
    __half* Q16     = (__half*)alloc((size_t)N * 128 * 2);  // f16 table B
    __half* zA      = (__half*)alloc((size_t)N * 64 * 2);
    __half* zB      = (__half*)alloc((size_t)N * 64 * 2);
    __half* evs     = (__half*)alloc((size_t)N * 64 * 2);
    float*  Wf      = (float*)alloc(128 * 64 * 4);
    float*  bf      = (float*)alloc(64 * 4);
    __half* W1t     = (__half*)alloc(128 * 256 * 2);
    __half* W2t     = (__half*)alloc(128 * 128 * 2);
    float*  ev      = (float*)d_out;  // f32 ev lives in d_out until final step

    const int nbN = (N + 255) / 256;
    const int nbE = (E + 255) / 256;
    const int nbP = (N + 3) / 4;      // wave-per-node kernels
    const int nbG = (N + 31) / 32;    // MFMA GEMM blocks (32 rows each)

    // --- CSR build + weight prep (fuseW/prepW independent of CSR) ---
    k_init<<<nbN, 256, 0, stream>>>(deg, N);
    k_count<<<nbE, 256, 0, stream>>>(edst, deg, rank, E);
    k_fuseW<<<1, 256, 0, stream>>>(Wc, bc, We, be, Wf, bf);
    k_prepW<<<(128 * 256 + 255) / 256, 256, 0, stream>>>(W1, W1t, 256);
    k_prepW<<<(128 * 128 + 255) / 256, 256, 0, stream>>>(W2, W2t, 128);
    k_scanA<<<nbN, 256, 0, stream>>>(deg, bs, N);
    k_scanB<<<1, 512, 0, stream>>>(bs, nbN);
    k_scanC<<<nbN, 256, 0, stream>>>(deg, bs, row_ptr, dinv, N);
    k_fill<<<nbE, 256, 0, stream>>>(esrc, edst, row_ptr, rank, csr_src, E);

    // --- GCN layer 1: P = f16(dinv * x@W1) via MFMA; Q16 = f16 relu prop ---
    k_mfma_gemm<256, false><<<nbG, 256, 0, stream>>>(x, W1t, dinv, P, N);
    k_prop2<128, 3><<<nbP, 256, 0, stream>>>(P, row_ptr, csr_src, dinv, b1, nullptr, Q16, N);

    // --- GCN layer 2: P = f16(dinv * Q16@W2) via MFMA; Q16 = f16 relu prop ---
    k_mfma_gemm<128, true><<<nbG, 256, 0, stream>>>(Q16, W2t, dinv, P, N);
    k_prop2<128, 3><<<nbP, 256, 0, stream>>>(P, row_ptr, csr_src, dinv, b2, nullptr, Q16, N);

    // --- fused classifier (f16 input): ev (f32, d_out) + evs (f16 scaled) ---
    k_cls<<<N / 32, 256, 0, stream>>>(Q16, Wf, bf, dinv, ev, evs, N);

    // --- APPNP: 9 scaled f16 iterations + final step fused w/ log_softmax ---
    const __half* zin = evs;
    __half* zout;
    for (int it = 0; it < 9; ++it) {
        zout = (it % 2 == 0) ? zA : zB;
        k_prop2<64, 1><<<nbP, 256, 0, stream>>>(zin, row_ptr, csr_src, dinv, nullptr, evs, zout, N);
        zin = zout;
    }
    // final: reads zA(f16) + ev(f32,d_out), writes log_softmax rows to d_out
    k_prop2<64, 2><<<nbP, 256, 0, stream>>>(zin, row_ptr, csr_src, dinv, nullptr, ev, (float*)d_out, N);
}

// Round 9
// 1065.090 us; speedup vs baseline: 2.6179x; 1.0127x over previous
//
#include <hip/hip_runtime.h>
#include <hip/hip_fp16.h>

// ---------------------------------------------------------------------------
// GPN_GCN: GCNConv x2 (MFMA f16 GEMMs, batched 2-phase LDS staging) -> fused
// classifier (Wc@We collapsed) -> APPNP(10, f16 scaled tables) -> log_softmax
// fused into last APPNP step. CSR per launch (rank trick: no fill atomics);
// props are wave-per-node half8 gathers, fp32 accumulate.
// ---------------------------------------------------------------------------

struct __align__(16) half8 { __half2 h[4]; };
typedef _Float16 f16x8 __attribute__((ext_vector_type(8)));
typedef float f32x4 __attribute__((ext_vector_type(4)));

__global__ __launch_bounds__(256) void k_init(int* deg, int N) {
    int i = blockIdx.x * 256 + threadIdx.x;
    if (i < N) deg[i] = 1;  // deg=1 accounts for self-loop
}

// atomicAdd return value = rank of edge within its dst.
__global__ __launch_bounds__(256) void k_count(const int* __restrict__ dst,
                                               int* deg, int* __restrict__ rank, int E) {
    int e = blockIdx.x * 256 + threadIdx.x;
    if (e < E) {
        int r = atomicAdd(&deg[dst[e]], 1);
        rank[e] = r - 1;
    }
}

__global__ __launch_bounds__(256) void k_scanA(const int* __restrict__ deg, int* bs, int N) {
    __shared__ int s[256];
    int t = threadIdx.x;
    int i = blockIdx.x * 256 + t;
    int c = (i < N) ? (deg[i] - 1) : 0;
    s[t] = c; __syncthreads();
    for (int o = 128; o > 0; o >>= 1) {
        if (t < o) s[t] += s[t + o];
        __syncthreads();
    }
    if (t == 0) bs[blockIdx.x] = s[0];
}

__global__ __launch_bounds__(512) void k_scanB(int* bs, int NB) {
    __shared__ int s[512];
    int t = threadIdx.x;
    int v = (t < NB) ? bs[t] : 0;
    s[t] = v; __syncthreads();
    for (int o = 1; o < 512; o <<= 1) {
        int u = (t >= o) ? s[t - o] : 0;
        __syncthreads();
        s[t] += u;
        __syncthreads();
    }
    if (t < NB) bs[t] = s[t] - v;  // exclusive
}

__global__ __launch_bounds__(256) void k_scanC(const int* __restrict__ deg, const int* __restrict__ bs,
                                               int* row_ptr, float* dinv, int N) {
    __shared__ int s[256];
    int t = threadIdx.x;
    int i = blockIdx.x * 256 + t;
    int c = (i < N) ? (deg[i] - 1) : 0;
    s[t] = c; __syncthreads();
    for (int o = 1; o < 256; o <<= 1) {
        int u = (t >= o) ? s[t - o] : 0;
        __syncthreads();
        s[t] += u;
        __syncthreads();
    }
    if (i < N) {
        int off = bs[blockIdx.x];
        row_ptr[i] = off + s[t] - c;          // exclusive
        dinv[i] = rsqrtf((float)deg[i]);
        if (i == N - 1) row_ptr[N] = off + s[t];
    }
}

// Atomic-free fill using precomputed ranks.
__global__ __launch_bounds__(256) void k_fill(const int* __restrict__ src, const int* __restrict__ dst,
                                              const int* __restrict__ row_ptr,
                                              const int* __restrict__ rank,
                                              int* __restrict__ csr_src, int E) {
    int e = blockIdx.x * 256 + threadIdx.x;
    if (e < E) csr_src[row_ptr[dst[e]] + rank[e]] = src[e];
}

// Wf = Wc @ We  [128x64], bf = bc @ We + be  [64]. One block.
__global__ __launch_bounds__(256) void k_fuseW(const float* __restrict__ Wc,
                                               const float* __restrict__ bc,
                                               const float* __restrict__ We,
                                               const float* __restrict__ be,
                                               float* __restrict__ Wf,
                                               float* __restrict__ bf) {
    __shared__ float sWe[64 * 64];
    int tid = threadIdx.x;
    for (int i = tid; i < 64 * 64 / 4; i += 256)
        ((float4*)sWe)[i] = ((const float4*)We)[i];
    __syncthreads();
    for (int idx = tid; idx < 128 * 64; idx += 256) {
        int r = idx >> 6, c = idx & 63;
        float s = 0.f;
#pragma unroll 8
        for (int j = 0; j < 64; j++) s += Wc[r * 64 + j] * sWe[j * 64 + c];
        Wf[idx] = s;
    }
    if (tid < 64) {
        float s = be[tid];
#pragma unroll 8
        for (int j = 0; j < 64; j++) s += bc[j] * sWe[j * 64 + tid];
        bf[tid] = s;
    }
}

// Wt[n][k] (f16, [128 x K]) = W[k][n] (f32, [K x 128]) — B-operand layout.
__global__ __launch_bounds__(256) void k_prepW(const float* __restrict__ W,
                                               __half* __restrict__ Wt, int K) {
    int idx = blockIdx.x * 256 + threadIdx.x;
    if (idx < 128 * K) {
        int n = idx / K, k = idx % K;
        Wt[idx] = __float2half(W[k * 128 + n]);
    }
}

// MFMA GEMM: Y[M,128](f16) = dinv[row] * (X[M,K] @ W[K,128]).
// 32 rows/block, 2x2 wave grid: wave = 16 rows x 4 col-tiles (64 cols).
// A staging is two-phase (batch-load into registers, then convert+ds_write)
// so all staging loads are in flight simultaneously. B preloaded in
// 128-k-halves (16 frags = 64 VGPR live) so the compiler keeps them resident.
// Frag layouts (m89/m120-verified): A[m=lane&15][k=quad*8+j],
// B[n=lane&15][k=quad*8+j], C/D col=lane&15, row=quad*4+reg.
template <int K, bool IN_F16>
__global__ __launch_bounds__(256) void k_mfma_gemm(const void* __restrict__ Xv,
                                                   const __half* __restrict__ Wt,
                                                   const float* __restrict__ dinv,
                                                   __half* __restrict__ Y, int N) {
    constexpr int PAD = 8;               // halves: row stride 264h=132w, 132%32=4 -> 2-way (free)
    constexpr int LDK = K + PAD;
    __shared__ __half sA[32 * LDK];
    int tid = threadIdx.x;
    int rowBase = blockIdx.x * 32;

    // --- two-phase A staging: all loads issued before any LDS write ---
    if (IN_F16) {
        constexpr int IT = 32 * (K / 8) / 256;   // 2 (K=128), 4 (K=256)
        half8 t[IT];
#pragma unroll
        for (int i = 0; i < IT; i++) {
            int idx = tid + i * 256;
            int r = idx / (K / 8), c8 = idx % (K / 8);
            int rg = rowBase + r; if (rg > N - 1) rg = N - 1;
            t[i] = *(const half8*)&((const __half*)Xv)[(long)rg * K + 8 * c8];
        }
#pragma unroll
        for (int i = 0; i < IT; i++) {
            int idx = tid + i * 256;
            int r = idx / (K / 8), c8 = idx % (K / 8);
            *(half8*)&sA[r * LDK + 8 * c8] = t[i];
        }
    } else {
        constexpr int IT = 32 * (K / 4) / 256;   // 8 (K=256)
        float4 t[IT];
#pragma unroll
        for (int i = 0; i < IT; i++) {
            int idx = tid + i * 256;
            int r = idx / (K / 4), c4 = idx % (K / 4);
            int rg = rowBase + r; if (rg > N - 1) rg = N - 1;
            t[i] = *(const float4*)&((const float*)Xv)[(long)rg * K + 4 * c4];
        }
#pragma unroll
        for (int i = 0; i < IT; i++) {
            int idx = tid + i * 256;
            int r = idx / (K / 4), c4 = idx % (K / 4);
            __half2* dst = (__half2*)&sA[r * LDK + 4 * c4];
            dst[0] = __floats2half2_rn(t[i].x, t[i].y);
            dst[1] = __floats2half2_rn(t[i].z, t[i].w);
        }
    }
    __syncthreads();

    int wave = tid >> 6, lane = tid & 63;
    int m = lane & 15, quad = lane >> 4;   // m doubles as n-within-tile for B
    int rw = (wave & 1) * 16;              // row half
    int cb = (wave >> 1) * 64;             // col half (4 tiles of 16)

    f32x4 d[4];
#pragma unroll
    for (int ct = 0; ct < 4; ct++) d[ct] = {0.f, 0.f, 0.f, 0.f};

#pragma unroll
    for (int kh = 0; kh < K / 128; kh++) {
        // preload this k-half's B fragments (4 kc x 4 ct = 64 VGPR)
        f16x8 bfr[4][4];
#pragma unroll
        for (int kc = 0; kc < 4; kc++)
#pragma unroll
            for (int ct = 0; ct < 4; ct++)
                bfr[kc][ct] = *(const f16x8*)&Wt[(long)(cb + ct * 16 + m) * K + kh * 128 + kc * 32 + quad * 8];
#pragma unroll
        for (int kc = 0; kc < 4; kc++) {
            const f16x8 a = *(const f16x8*)&sA[(rw + m) * LDK + kh * 128 + kc * 32 + quad * 8];
#pragma unroll
            for (int ct = 0; ct < 4; ct++)
                d[ct] = __builtin_amdgcn_mfma_f32_16x16x32_f16(a, bfr[kc][ct], d[ct], 0, 0, 0);
        }
    }

#pragma unroll
    for (int ct = 0; ct < 4; ct++) {
        int col = cb + ct * 16 + m;
#pragma unroll
        for (int reg = 0; reg < 4; reg++) {
            int row = rowBase + rw + quad * 4 + reg;
            if (row < N)
                Y[(long)row * 128 + col] = __float2half(d[ct][reg] * dinv[row]);
        }
    }
}

// Fused classifier (f16 input): ev(f32,d_out) = relu(H @ Wf + bf);
// evs(f16) = dinv (.) ev.
__global__ __launch_bounds__(256) void k_cls(const __half* __restrict__ H,
                                             const float* __restrict__ Wf,
                                             const float* __restrict__ bf,
                                             const float* __restrict__ dinv,
                                             float* __restrict__ ev,
                                             __half* __restrict__ evs, int N) {
    __shared__ __half sH[32 * 128];
    int tid = threadIdx.x;
    long rowBase = (long)blockIdx.x * 32;
    const half8* xg = (const half8*)(H + rowBase * 128);
    {
        half8 t0 = xg[tid];
        half8 t1 = xg[tid + 256];
        ((half8*)sH)[tid] = t0;
        ((half8*)sH)[tid + 256] = t1;
    }
    __syncthreads();

    int col = tid & 63;
    int r0 = (tid >> 6) * 8;
    float acc[8];
#pragma unroll
    for (int r = 0; r < 8; r++) acc[r] = 0.f;

    for (int k = 0; k < 128; k += 4) {
        float w0 = Wf[(k + 0) * 64 + col];
        float w1 = Wf[(k + 1) * 64 + col];
        float w2 = Wf[(k + 2) * 64 + col];
        float w3 = Wf[(k + 3) * 64 + col];
#pragma unroll
        for (int r = 0; r < 8; r++) {
            const __half2 h01 = *(const __half2*)&sH[(r0 + r) * 128 + k];
            const __half2 h23 = *(const __half2*)&sH[(r0 + r) * 128 + k + 2];
            float2 f01 = __half22float2(h01);
            float2 f23 = __half22float2(h23);
            acc[r] += f01.x * w0 + f01.y * w1 + f23.x * w2 + f23.y * w3;
        }
    }
    float b = bf[col];
#pragma unroll
    for (int r = 0; r < 8; r++) {
        long row = rowBase + r0 + r;
        float v = fmaxf(acc[r] + b, 0.f);
        ev[row * 64 + col] = v;
        evs[row * 64 + col] = __float2half(v * dinv[row]);
    }
}

// Wave-per-node gather propagation over fp16 scaled table tab = dinv (.) h.
// A = sum_{src in nbr(i)} tab[src] + tab[i]
// MODE 3 (GCN, f16):    out(f16) = relu(di*A + bias)   (unscaled, next input)
// MODE 1 (APPNP inner): out(f16) = 0.9*di^2*A + 0.1*evs[i]   (scaled space)
// MODE 2 (APPNP final): out(f32) = log_softmax(0.9*di*A + 0.1*ev[i])
template <int F, int MODE>
__global__ __launch_bounds__(256) void k_prop2(const __half* __restrict__ tab,
                                               const int* __restrict__ row_ptr,
                                               const int* __restrict__ csr_src,
                                               const float* __restrict__ dinv,
                                               const float* __restrict__ bias,
                                               const void* __restrict__ evx,
                                               void* __restrict__ out, int N) {
    constexpr int LPE = F / 8;    // lanes per edge-slot (half8 = 8 feats each)
    constexpr int S = 64 / LPE;   // edge slots per wave
    int wave = threadIdx.x >> 6;
    int lane = threadIdx.x & 63;
    int node = blockIdx.x * 4 + wave;
    if (node >= N) return;
    int slot = lane / LPE;
    int fl = lane % LPE;          // features 8*fl .. 8*fl+7
    const int2 se = *(const int2*)&row_ptr[node];
    int s = se.x, e = se.y;

    float acc[8], accB[8];
#pragma unroll
    for (int q = 0; q < 8; q++) { acc[q] = 0.f; accB[q] = 0.f; }

    int j = s + slot;
    for (; j + S < e; j += 2 * S) {
        const half8 a = *(const half8*)&tab[(long)csr_src[j] * F + 8 * fl];
        const half8 b = *(const half8*)&tab[(long)csr_src[j + S] * F + 8 * fl];
#pragma unroll
        for (int q = 0; q < 4; q++) {
            float2 fa = __half22float2(a.h[q]);
            float2 fb = __half22float2(b.h[q]);
            acc[2 * q] += fa.x; acc[2 * q + 1] += fa.y;
            accB[2 * q] += fb.x; accB[2 * q + 1] += fb.y;
        }
    }
    if (j < e) {
        const half8 a = *(const half8*)&tab[(long)csr_src[j] * F + 8 * fl];
#pragma unroll
        for (int q = 0; q < 4; q++) {
            float2 fa = __half22float2(a.h[q]);
            acc[2 * q] += fa.x; acc[2 * q + 1] += fa.y;
        }
    }
    if (slot == 0) {  // self loop
        const half8 a = *(const half8*)&tab[(long)node * F + 8 * fl];
#pragma unroll
        for (int q = 0; q < 4; q++) {
            float2 fa = __half22float2(a.h[q]);
            acc[2 * q] += fa.x; acc[2 * q + 1] += fa.y;
        }
    }
#pragma unroll
    for (int q = 0; q < 8; q++) acc[q] += accB[q];

#pragma unroll
    for (int off = LPE; off < 64; off <<= 1) {
#pragma unroll
        for (int q = 0; q < 8; q++) acc[q] += __shfl_xor(acc[q], off, 64);
    }

    if (slot == 0) {
        float di = dinv[node];
        if (MODE == 3) {
            const float4 b0 = *(const float4*)&bias[8 * fl];
            const float4 b1 = *(const float4*)&bias[8 * fl + 4];
            half8 ov;
            ov.h[0] = __floats2half2_rn(fmaxf(di * acc[0] + b0.x, 0.f),
                                        fmaxf(di * acc[1] + b0.y, 0.f));
            ov.h[1] = __floats2half2_rn(fmaxf(di * acc[2] + b0.z, 0.f),
                                        fmaxf(di * acc[3] + b0.w, 0.f));
            ov.h[2] = __floats2half2_rn(fmaxf(di * acc[4] + b1.x, 0.f),
                                        fmaxf(di * acc[5] + b1.y, 0.f));
            ov.h[3] = __floats2half2_rn(fmaxf(di * acc[6] + b1.z, 0.f),
                                        fmaxf(di * acc[7] + b1.w, 0.f));
            *(half8*)&((__half*)out)[(long)node * F + 8 * fl] = ov;
        } else if (MODE == 1) {
            float d2 = 0.9f * di * di;
            const half8 eh = *(const half8*)&((const __half*)evx)[(long)node * F + 8 * fl];
            half8 ov;
#pragma unroll
            for (int q = 0; q < 4; q++) {
                float2 ef = __half22float2(eh.h[q]);
                float vx = d2 * acc[2 * q] + 0.1f * ef.x;
                float vy = d2 * acc[2 * q + 1] + 0.1f * ef.y;
                ov.h[q] = __floats2half2_rn(vx, vy);
            }
            *(half8*)&((__half*)out)[(long)node * F + 8 * fl] = ov;
        } else {
            // final APPNP step fused with log_softmax (F==64: lanes 0..7
            // of each wave hold the full 64-class row, 8 classes each)
            float d1 = 0.9f * di;
            const float* ef = (const float*)evx + (long)node * F + 8 * fl;
            const float4 e0 = *(const float4*)ef;
            const float4 e1 = *(const float4*)(ef + 4);
            float v[8];
            v[0] = d1 * acc[0] + 0.1f * e0.x;
            v[1] = d1 * acc[1] + 0.1f * e0.y;
            v[2] = d1 * acc[2] + 0.1f * e0.z;
            v[3] = d1 * acc[3] + 0.1f * e0.w;
            v[4] = d1 * acc[4] + 0.1f * e1.x;
            v[5] = d1 * acc[5] + 0.1f * e1.y;
            v[6] = d1 * acc[6] + 0.1f * e1.z;
            v[7] = d1 * acc[7] + 0.1f * e1.w;
            float m = v[0];
#pragma unroll
            for (int q = 1; q < 8; q++) m = fmaxf(m, v[q]);
#pragma unroll
            for (int off = 1; off < LPE; off <<= 1) m = fmaxf(m, __shfl_xor(m, off, 64));
            float ssum = 0.f;
#pragma unroll
            for (int q = 0; q < 8; q++) ssum += __expf(v[q] - m);
#pragma unroll
            for (int off = 1; off < LPE; off <<= 1) ssum += __shfl_xor(ssum, off, 64);
            float lse = m + __logf(ssum);
            float* o = (float*)out + (long)node * F + 8 * fl;
            float4 v0, v1;
            v0.x = v[0] - lse; v0.y = v[1] - lse; v0.z = v[2] - lse; v0.w = v[3] - lse;
            v1.x = v[4] - lse; v1.y = v[5] - lse; v1.z = v[6] - lse; v1.w = v[7] - lse;
            *(float4*)o = v0;
            *(float4*)(o + 4) = v1;
        }
    }
}

extern "C" void kernel_launch(void* const* d_in, const int* in_sizes, int n_in,
                              void* d_out, int out_size, void* d_ws, size_t ws_size,
                              hipStream_t stream) {
    const float* x  = (const float*)d_in[0];
    const int* edges = (const int*)d_in[1];
    const float* W1 = (const float*)d_in[2];
    const float* b1 = (const float*)d_in[3];
    const float* W2 = (const float*)d_in[4];
    const float* b2 = (const float*)d_in[5];
    const float* Wc = (const float*)d_in[6];
    const float* bc = (const float*)d_in[7];
    const float* We = (const float*)d_in[8];
    const float* be = (const float*)d_in[9];

    const int N = in_sizes[0] / 256;   // 100000
    const int E = in_sizes[1] / 2;     // 1600000
    const int* esrc = edges;
    const int* edst = edges + E;

    char* ws = (char*)d_ws;
    size_t off = 0;
    auto alloc = [&](size_t bytes) -> void* {
        void* p = ws + off;
        off += (bytes + 255) & ~(size_t)255;
        return p;
    };
    int*    deg     = (int*)alloc((size_t)N * 4);
    int*    row_ptr = (int*)alloc((size_t)(N + 1) * 4);
    float*  dinv    = (float*)alloc((size_t)N * 4);
    int*    bs      = (int*)alloc(4096 * 4);
    int*    rank    = (int*)alloc((size_t)E * 4);
    int*    csr_src = (int*)alloc((size_t)E * 4);
    __half* P       = (__half*)alloc((size_t)N * 128 * 2);  // f16 table A
    __half* Q16     = (__half*)alloc((size_t)N * 128 * 2);  // f16 table B
    __half* zA      = (__half*)alloc((size_t)N * 64 * 2);
    __half* zB      = (__half*)alloc((size_t)N * 64 * 2);
    __half* evs     = (__half*)alloc((size_t)N * 64 * 2);
    float*  Wf      = (float*)alloc(128 * 64 * 4);
    float*  bf      = (float*)alloc(64 * 4);
    __half* W1t     = (__half*)alloc(128 * 256 * 2);
    __half* W2t     = (__half*)alloc(128 * 128 * 2);
    float*  ev      = (float*)d_out;  // f32 ev lives in d_out until final step

    const int nbN = (N + 255) / 256;
    const int nbE = (E + 255) / 256;
    const int nbP = (N + 3) / 4;      // wave-per-node kernels
    const int nbG = (N + 31) / 32;    // MFMA GEMM blocks (32 rows each)

    // --- CSR build + weight prep (fuseW/prepW independent of CSR) ---
    k_init<<<nbN, 256, 0, stream>>>(deg, N);
    k_count<<<nbE, 256, 0, stream>>>(edst, deg, rank, E);
    k_fuseW<<<1, 256, 0, stream>>>(Wc, bc, We, be, Wf, bf);
    k_prepW<<<(128 * 256 + 255) / 256, 256, 0, stream>>>(W1, W1t, 256);
    k_prepW<<<(128 * 128 + 255) / 256, 256, 0, stream>>>(W2, W2t, 128);
    k_scanA<<<nbN, 256, 0, stream>>>(deg, bs, N);
    k_scanB<<<1, 512, 0, stream>>>(bs, nbN);
    k_scanC<<<nbN, 256, 0, stream>>>(deg, bs, row_ptr, dinv, N);
    k_fill<<<nbE, 256, 0, stream>>>(esrc, edst, row_ptr, rank, csr_src, E);

    // --- GCN layer 1: P = f16(dinv * x@W1) via MFMA; Q16 = f16 relu prop ---
    k_mfma_gemm<256, false><<<nbG, 256, 0, stream>>>(x, W1t, dinv, P, N);
    k_prop2<128, 3><<<nbP, 256, 0, stream>>>(P, row_ptr, csr_src, dinv, b1, nullptr, Q16, N);

    // --- GCN layer 2: P = f16(dinv * Q16@W2) via MFMA; Q16 = f16 relu prop ---
    k_mfma_gemm<128, true><<<nbG, 256, 0, stream>>>(Q16, W2t, dinv, P, N);
    k_prop2<128, 3><<<nbP, 256, 0, stream>>>(P, row_ptr, csr_src, dinv, b2, nullptr, Q16, N);

    // --- fused classifier (f16 input): ev (f32, d_out) + evs (f16 scaled) ---
    k_cls<<<N / 32, 256, 0, stream>>>(Q16, Wf, bf, dinv, ev, evs, N);

    // --- APPNP: 9 scaled f16 iterations + final step fused w/ log_softmax ---
    const __half* zin = evs;
    __half* zout;
    for (int it = 0; it < 9; ++it) {
        zout = (it % 2 == 0) ? zA : zB;
        k_prop2<64, 1><<<nbP, 256, 0, stream>>>(zin, row_ptr, csr_src, dinv, nullptr, evs, zout, N);
        zin = zout;
    }
    // final: reads zA(f16) + ev(f32,d_out), writes log_softmax rows to d_out
    k_prop2<64, 2><<<nbP, 256, 0, stream>>>(zin, row_ptr, csr_src, dinv, nullptr, ev, (float*)d_out, N);
}